// Round 2
// baseline (197.223 us; speedup 1.0000x reference)
//
#include <hip/hip_runtime.h>

typedef unsigned short u16;
typedef unsigned int u32;
typedef __attribute__((ext_vector_type(8))) short short8;
typedef __attribute__((ext_vector_type(4))) float f32x4;

#define GLOBAL_AS(p) (const __attribute__((address_space(1))) void*)(p)
#define LDS_AS(p) (__attribute__((address_space(3))) void*)(p)

__device__ __forceinline__ u16 f2b(float f) {
  u32 u = __float_as_uint(f);
  u32 r = (u + 0x7fffu + ((u >> 16) & 1u)) >> 16;
  return (u16)r;
}
__device__ __forceinline__ float blo(u32 u) { return __uint_as_float(u << 16); }
__device__ __forceinline__ float bhi(u32 u) { return __uint_as_float(u & 0xffff0000u); }

// ---------------- fp32 -> bf16 convert (x) ----------------
__global__ void conv_bf16(const float* __restrict__ in, u16* __restrict__ out, int n4) {
  int i = blockIdx.x * blockDim.x + threadIdx.x;
  int stride = gridDim.x * blockDim.x;
  for (; i < n4; i += stride) {
    float4 f = ((const float4*)in)[i];
    ushort4 u;
    u.x = f2b(f.x); u.y = f2b(f.y); u.z = f2b(f.z); u.w = f2b(f.w);
    ((ushort4*)out)[i] = u;
  }
}

// ---------- fp32 (R x C) -> bf16 transposed (C x R) ----------
__global__ void transpose_conv(const float* __restrict__ in, u16* __restrict__ out,
                               int R, int Cc) {
  __shared__ float tile[32][33];
  int c0 = blockIdx.x * 32, r0 = blockIdx.y * 32;
  int tx = threadIdx.x, ty = threadIdx.y;  // 32 x 8
#pragma unroll
  for (int i = 0; i < 32; i += 8)
    tile[ty + i][tx] = in[(size_t)(r0 + ty + i) * Cc + c0 + tx];
  __syncthreads();
#pragma unroll
  for (int i = 0; i < 32; i += 8)
    out[(size_t)(c0 + ty + i) * R + r0 + tx] = f2b(tile[tx][ty + i]);
}

// ---------------- GEMM: C = A(MxK) * Bt(NxK)^T, bf16 in, fp32 acc ----------------
// EPI=0: store bf16.  EPI=1: store fp32 + bias.
template <int EPI>
__global__ __launch_bounds__(256) void gemm_bt(
    const u16* __restrict__ A, const u16* __restrict__ Bt, void* __restrict__ Cout,
    const float* __restrict__ bias, int M, int N, int K) {
  __shared__ u16 lA[128 * 32];
  __shared__ u16 lB[128 * 32];
  const int t = threadIdx.x;
  const int n0 = blockIdx.x * 128, m0 = blockIdx.y * 128;
  const int wv = t >> 6, l = t & 63;
  const int wm = wv >> 1, wn = wv & 1;
  const int lr = l & 15, g = l >> 4;
  f32x4 acc[4][4] = {};

  for (int kt = 0; kt < K; kt += 32) {
#pragma unroll
    for (int i = 0; i < 2; ++i) {
      int fc = t + i * 256;           // 16B chunk id, 0..511
      int row = fc >> 2, c = fc & 3;  // row in tile, chunk-in-row
      int gc = c ^ ((row >> 1) & 3);  // pre-swizzled global chunk
      const u16* gA = A + (size_t)(m0 + row) * K + kt + gc * 8;
      __builtin_amdgcn_global_load_lds(GLOBAL_AS(gA), LDS_AS(lA + fc * 8), 16, 0, 0);
      const u16* gB = Bt + (size_t)(n0 + row) * K + kt + gc * 8;
      __builtin_amdgcn_global_load_lds(GLOBAL_AS(gB), LDS_AS(lB + fc * 8), 16, 0, 0);
    }
    __syncthreads();  // drains vmcnt, staging visible

    short8 af[4], bf[4];
#pragma unroll
    for (int mi = 0; mi < 4; ++mi) {
      int row = wm * 64 + mi * 16 + lr;
      af[mi] = *(const short8*)(lA + row * 32 + (g ^ ((row >> 1) & 3)) * 8);
    }
#pragma unroll
    for (int ni = 0; ni < 4; ++ni) {
      int row = wn * 64 + ni * 16 + lr;
      bf[ni] = *(const short8*)(lB + row * 32 + (g ^ ((row >> 1) & 3)) * 8);
    }
#pragma unroll
    for (int mi = 0; mi < 4; ++mi)
#pragma unroll
      for (int ni = 0; ni < 4; ++ni)
        acc[mi][ni] =
            __builtin_amdgcn_mfma_f32_16x16x32_bf16(af[mi], bf[ni], acc[mi][ni], 0, 0, 0);
    __syncthreads();  // protect LDS before next stage
  }

#pragma unroll
  for (int mi = 0; mi < 4; ++mi) {
    int row = m0 + wm * 64 + mi * 16 + g * 4;
#pragma unroll
    for (int ni = 0; ni < 4; ++ni) {
      int col = n0 + wn * 64 + ni * 16 + lr;
#pragma unroll
      for (int r = 0; r < 4; ++r) {
        float v = acc[mi][ni][r];
        if (EPI == 0) {
          ((u16*)Cout)[(size_t)(row + r) * N + col] = f2b(v);
        } else {
          ((float*)Cout)[(size_t)(row + r) * N + col] = v + bias[col];
        }
      }
    }
  }
}

// ---------------- local attention ----------------
// qkv: (B*N, 2304) bf16 rows: [q(768) | k(768) | v(768)], within each: h*64+d
// attn out: (B*N, 768) bf16
#define NTILE 128
#define ROWS 140  // NTILE + 2*6
#define LPAD 66

__global__ __launch_bounds__(128) void attn_kernel(const u16* __restrict__ qkv,
                                                   u16* __restrict__ attn) {
  const int nt = blockIdx.x, h = blockIdx.y, b = blockIdx.z;
  const int n0 = nt * NTILE;
  const int t = threadIdx.x;
  __shared__ u16 kl[ROWS * LPAD];
  __shared__ u16 vl[ROWS * LPAD];

  // stage K and V window rows [n0-6, n0+NTILE+5] (clamped) into LDS
  for (int i = t; i < 2 * ROWS * 8; i += 128) {
    int mat = i >= ROWS * 8;
    int j = mat ? i - ROWS * 8 : i;
    int r = j >> 3, c = j & 7;
    int grow = n0 - 6 + r;
    grow = grow < 0 ? 0 : (grow > 4095 ? 4095 : grow);
    const uint4 u =
        *(const uint4*)(qkv + (size_t)(b * 4096 + grow) * 2304 + (mat ? 1536 : 768) + h * 64 + c * 8);
    u16* dst = (mat ? vl : kl) + r * LPAD + c * 8;
    ((u32*)dst)[0] = u.x;
    ((u32*)dst)[1] = u.y;
    ((u32*)dst)[2] = u.z;
    ((u32*)dst)[3] = u.w;
  }
  __syncthreads();

  const int wv = t >> 6, l = t & 63;
  const int n = n0 + wv * 64 + l;
  const int lrow = wv * 64 + l;  // LDS row for w=0 is lrow (+w walks window)

  // q into registers (fp32)
  float qf[64];
  const u16* qp = qkv + (size_t)(b * 4096 + n) * 2304 + h * 64;
#pragma unroll
  for (int c = 0; c < 8; ++c) {
    uint4 u = *(const uint4*)(qp + c * 8);
    qf[c * 8 + 0] = blo(u.x); qf[c * 8 + 1] = bhi(u.x);
    qf[c * 8 + 2] = blo(u.y); qf[c * 8 + 3] = bhi(u.y);
    qf[c * 8 + 4] = blo(u.z); qf[c * 8 + 5] = bhi(u.z);
    qf[c * 8 + 6] = blo(u.w); qf[c * 8 + 7] = bhi(u.w);
  }

  float s[13];
#pragma unroll
  for (int w = 0; w < 13; ++w) s[w] = 0.f;
#pragma unroll
  for (int d2 = 0; d2 < 32; ++d2) {
    float q0 = qf[2 * d2], q1 = qf[2 * d2 + 1];
#pragma unroll
    for (int w = 0; w < 13; ++w) {
      u32 u = *(const u32*)(kl + (lrow + w) * LPAD + 2 * d2);
      s[w] += q0 * blo(u) + q1 * bhi(u);
    }
  }

  // mask + softmax (fp32)
#pragma unroll
  for (int w = 0; w < 13; ++w) {
    int nn = n - 6 + w;
    s[w] = (nn >= 0 && nn < 4096) ? s[w] * 0.125f : -1e30f;
  }
  float m = s[0];
#pragma unroll
  for (int w = 1; w < 13; ++w) m = fmaxf(m, s[w]);
  float sum = 0.f;
#pragma unroll
  for (int w = 0; w < 13; ++w) {
    float p = __expf(s[w] - m);
    s[w] = p;
    sum += p;
  }
  float inv = 1.0f / sum;

  float o[64];
#pragma unroll
  for (int d = 0; d < 64; ++d) o[d] = 0.f;
#pragma unroll
  for (int w = 0; w < 13; ++w) {
    float pw = s[w] * inv;
#pragma unroll
    for (int d2 = 0; d2 < 32; ++d2) {
      u32 u = *(const u32*)(vl + (lrow + w) * LPAD + 2 * d2);
      o[2 * d2] += pw * blo(u);
      o[2 * d2 + 1] += pw * bhi(u);
    }
  }

  u16* op = attn + (size_t)(b * 4096 + n) * 768 + h * 64;
#pragma unroll
  for (int c = 0; c < 8; ++c) {
    uint4 u;
    u.x = (u32)f2b(o[c * 8 + 0]) | ((u32)f2b(o[c * 8 + 1]) << 16);
    u.y = (u32)f2b(o[c * 8 + 2]) | ((u32)f2b(o[c * 8 + 3]) << 16);
    u.z = (u32)f2b(o[c * 8 + 4]) | ((u32)f2b(o[c * 8 + 5]) << 16);
    u.w = (u32)f2b(o[c * 8 + 6]) | ((u32)f2b(o[c * 8 + 7]) << 16);
    ((uint4*)op)[c] = u;
  }
}

extern "C" void kernel_launch(void* const* d_in, const int* in_sizes, int n_in,
                              void* d_out, int out_size, void* d_ws, size_t ws_size,
                              hipStream_t stream) {
  const float* x = (const float*)d_in[0];
  const float* w_qkv = (const float*)d_in[1];
  const float* w_proj = (const float*)d_in[2];
  const float* b_proj = (const float*)d_in[3];
  float* out = (float*)d_out;

  char* p = (char*)d_ws;
  u16* xb = (u16*)p;     p += (size_t)8192 * 768 * 2;   // x bf16
  u16* wqT = (u16*)p;    p += (size_t)2304 * 768 * 2;   // w_qkv^T bf16
  u16* wpT = (u16*)p;    p += (size_t)768 * 768 * 2;    // w_proj^T bf16
  u16* qkvb = (u16*)p;   p += (size_t)8192 * 2304 * 2;  // qkv bf16
  u16* attnb = (u16*)p;  p += (size_t)8192 * 768 * 2;   // attn out bf16

  conv_bf16<<<dim3(1024), dim3(256), 0, stream>>>(x, xb, 8192 * 768 / 4);
  transpose_conv<<<dim3(2304 / 32, 768 / 32), dim3(32, 8), 0, stream>>>(w_qkv, wqT, 768, 2304);
  transpose_conv<<<dim3(768 / 32, 768 / 32), dim3(32, 8), 0, stream>>>(w_proj, wpT, 768, 768);

  gemm_bt<0><<<dim3(2304 / 128, 8192 / 128), dim3(256), 0, stream>>>(
      xb, wqT, (void*)qkvb, nullptr, 8192, 2304, 768);

  attn_kernel<<<dim3(4096 / NTILE, 12, 2), dim3(128), 0, stream>>>(qkvb, attnb);

  gemm_bt<1><<<dim3(768 / 128, 8192 / 128), dim3(256), 0, stream>>>(
      attnb, wpT, (void*)out, b_proj, 8192, 768, 768);
}

// Round 3
// 189.743 us; speedup vs baseline: 1.0394x; 1.0394x over previous
//
#include <hip/hip_runtime.h>

typedef unsigned short u16;
typedef unsigned int u32;
typedef __attribute__((ext_vector_type(8))) short short8;
typedef __attribute__((ext_vector_type(4))) float f32x4;

#define GLOBAL_AS(p) (const __attribute__((address_space(1))) void*)(p)
#define LDS_AS(p) (__attribute__((address_space(3))) void*)(p)

__device__ __forceinline__ u16 f2b(float f) {
  u32 u = __float_as_uint(f);
  u32 r = (u + 0x7fffu + ((u >> 16) & 1u)) >> 16;
  return (u16)r;
}
__device__ __forceinline__ float blo(u32 u) { return __uint_as_float(u << 16); }
__device__ __forceinline__ float bhi(u32 u) { return __uint_as_float(u & 0xffff0000u); }

// ---------------- fp32 -> bf16 convert (x) ----------------
__global__ void conv_bf16(const float* __restrict__ in, u16* __restrict__ out, int n4) {
  int i = blockIdx.x * blockDim.x + threadIdx.x;
  int stride = gridDim.x * blockDim.x;
  for (; i < n4; i += stride) {
    float4 f = ((const float4*)in)[i];
    ushort4 u;
    u.x = f2b(f.x); u.y = f2b(f.y); u.z = f2b(f.z); u.w = f2b(f.w);
    ((ushort4*)out)[i] = u;
  }
}

// ---------- fp32 (R x C) -> bf16 transposed (C x R) ----------
__global__ void transpose_conv(const float* __restrict__ in, u16* __restrict__ out,
                               int R, int Cc) {
  __shared__ float tile[32][33];
  int c0 = blockIdx.x * 32, r0 = blockIdx.y * 32;
  int tx = threadIdx.x, ty = threadIdx.y;  // 32 x 8
#pragma unroll
  for (int i = 0; i < 32; i += 8)
    tile[ty + i][tx] = in[(size_t)(r0 + ty + i) * Cc + c0 + tx];
  __syncthreads();
#pragma unroll
  for (int i = 0; i < 32; i += 8)
    out[(size_t)(c0 + ty + i) * R + r0 + tx] = f2b(tile[tx][ty + i]);
}

// ---------------- 8-phase-style GEMM: C = A(MxK) * Bt(NxK)^T ----------------
// BM=128, BN=256, BK=32, K=768 (NT=24 tiles), 512 threads = 8 waves (2M x 4N),
// per-wave output 64x64. 4-tile LDS ring (96 KiB), counted vmcnt(6), raw
// s_barrier (no vmcnt(0) drain in main loop), setprio around MFMA cluster.
// Swizzle: chunk' = chunk ^ ((row>>3 & 1) << 1), applied on BOTH the staging
// global source and the ds_read address (involution).
#define G8_NT 24

#define PHASE(KT, DOSTAGE, VM)                                                          \
  do {                                                                                  \
    asm volatile("s_waitcnt vmcnt(" VM ")" ::: "memory");                               \
    __builtin_amdgcn_s_barrier();                                                       \
    asm volatile("" ::: "memory");                                                      \
    const int bb_ = (KT) & 3;                                                           \
    const u16* pa_ = lA + bb_ * 4096;                                                   \
    const u16* pb_ = lB + bb_ * 8192;                                                   \
    short8 af0 = *(const short8*)(pa_ + aoff0);                                         \
    short8 af1 = *(const short8*)(pa_ + aoff1);                                         \
    short8 af2 = *(const short8*)(pa_ + aoff2);                                         \
    short8 af3 = *(const short8*)(pa_ + aoff3);                                         \
    short8 bf0 = *(const short8*)(pb_ + boff0);                                         \
    short8 bf1 = *(const short8*)(pb_ + boff1);                                         \
    short8 bf2 = *(const short8*)(pb_ + boff2);                                         \
    short8 bf3 = *(const short8*)(pb_ + boff3);                                         \
    if (DOSTAGE) {                                                                      \
      const int sb_ = ((KT) + 3) & 3;                                                   \
      __builtin_amdgcn_global_load_lds(GLOBAL_AS(gAs + ((KT) + 3) * 32),                \
                                       LDS_AS(lA + sb_ * 4096 + t * 8), 16, 0, 0);      \
      __builtin_amdgcn_global_load_lds(GLOBAL_AS(gB0s + ((KT) + 3) * 32),               \
                                       LDS_AS(lB + sb_ * 8192 + t * 8), 16, 0, 0);      \
      __builtin_amdgcn_global_load_lds(GLOBAL_AS(gB1s + ((KT) + 3) * 32),               \
                                       LDS_AS(lB + sb_ * 8192 + (t + 512) * 8), 16, 0, 0); \
    }                                                                                   \
    __builtin_amdgcn_s_setprio(1);                                                      \
    acc[0][0] = __builtin_amdgcn_mfma_f32_16x16x32_bf16(af0, bf0, acc[0][0], 0, 0, 0);  \
    acc[0][1] = __builtin_amdgcn_mfma_f32_16x16x32_bf16(af0, bf1, acc[0][1], 0, 0, 0);  \
    acc[0][2] = __builtin_amdgcn_mfma_f32_16x16x32_bf16(af0, bf2, acc[0][2], 0, 0, 0);  \
    acc[0][3] = __builtin_amdgcn_mfma_f32_16x16x32_bf16(af0, bf3, acc[0][3], 0, 0, 0);  \
    acc[1][0] = __builtin_amdgcn_mfma_f32_16x16x32_bf16(af1, bf0, acc[1][0], 0, 0, 0);  \
    acc[1][1] = __builtin_amdgcn_mfma_f32_16x16x32_bf16(af1, bf1, acc[1][1], 0, 0, 0);  \
    acc[1][2] = __builtin_amdgcn_mfma_f32_16x16x32_bf16(af1, bf2, acc[1][2], 0, 0, 0);  \
    acc[1][3] = __builtin_amdgcn_mfma_f32_16x16x32_bf16(af1, bf3, acc[1][3], 0, 0, 0);  \
    acc[2][0] = __builtin_amdgcn_mfma_f32_16x16x32_bf16(af2, bf0, acc[2][0], 0, 0, 0);  \
    acc[2][1] = __builtin_amdgcn_mfma_f32_16x16x32_bf16(af2, bf1, acc[2][1], 0, 0, 0);  \
    acc[2][2] = __builtin_amdgcn_mfma_f32_16x16x32_bf16(af2, bf2, acc[2][2], 0, 0, 0);  \
    acc[2][3] = __builtin_amdgcn_mfma_f32_16x16x32_bf16(af2, bf3, acc[2][3], 0, 0, 0);  \
    acc[3][0] = __builtin_amdgcn_mfma_f32_16x16x32_bf16(af3, bf0, acc[3][0], 0, 0, 0);  \
    acc[3][1] = __builtin_amdgcn_mfma_f32_16x16x32_bf16(af3, bf1, acc[3][1], 0, 0, 0);  \
    acc[3][2] = __builtin_amdgcn_mfma_f32_16x16x32_bf16(af3, bf2, acc[3][2], 0, 0, 0);  \
    acc[3][3] = __builtin_amdgcn_mfma_f32_16x16x32_bf16(af3, bf3, acc[3][3], 0, 0, 0);  \
    __builtin_amdgcn_s_setprio(0);                                                      \
    asm volatile("" ::: "memory");                                                      \
    __builtin_amdgcn_s_barrier();                                                       \
  } while (0)

template <int EPI>
__global__ __launch_bounds__(512, 1) void gemm8p(
    const u16* __restrict__ A, const u16* __restrict__ Bt, void* __restrict__ Cout,
    const float* __restrict__ bias, int M, int N, int K) {
  extern __shared__ u16 sm[];
  u16* lA = sm;              // 4 bufs x 128 rows x 32 cols = 4*4096 u16 (32 KiB)
  u16* lB = sm + 4 * 4096;   // 4 bufs x 256 rows x 32 cols = 4*8192 u16 (64 KiB)
  const int t = threadIdx.x;
  const int n0 = blockIdx.x * 256, m0 = blockIdx.y * 128;
  const int wv = t >> 6, l = t & 63;
  const int wm = wv >> 2, wn = wv & 3;  // wave tile: rows wm*64, cols wn*64
  const int lr = l & 15, g = l >> 4;

  // staging source (pre-swizzled): chunk cid -> row cid>>2, src col-chunk
  // (cid&3) ^ ((cid>>5 & 1)<<1); note (t+512) has same swizzle bit as t.
  const int ra = t >> 2;
  const int ca = (t & 3) ^ (((t >> 5) & 1) << 1);
  const u16* gAs = A + (size_t)(m0 + ra) * K + ca * 8;
  const u16* gB0s = Bt + (size_t)(n0 + ra) * K + ca * 8;
  const u16* gB1s = Bt + (size_t)(n0 + ra + 128) * K + ca * 8;

  // fragment ds_read offsets (u16 units): row rr -> rr*32 + (g ^ ((l>>3&1)<<1))*8
  const int cswz = (g ^ (((l >> 3) & 1) << 1)) * 8;
  const int ar = wm * 64 + lr;
  const int br = wn * 64 + lr;
  const int aoff0 = (ar + 0) * 32 + cswz, aoff1 = (ar + 16) * 32 + cswz;
  const int aoff2 = (ar + 32) * 32 + cswz, aoff3 = (ar + 48) * 32 + cswz;
  const int boff0 = (br + 0) * 32 + cswz, boff1 = (br + 16) * 32 + cswz;
  const int boff2 = (br + 32) * 32 + cswz, boff3 = (br + 48) * 32 + cswz;

  f32x4 acc[4][4] = {};

  // prologue: stage tiles 0,1,2 (issue order = tile-major for vmcnt counting)
#pragma unroll
  for (int j = 0; j < 3; ++j) {
    __builtin_amdgcn_global_load_lds(GLOBAL_AS(gAs + j * 32),
                                     LDS_AS(lA + j * 4096 + t * 8), 16, 0, 0);
    __builtin_amdgcn_global_load_lds(GLOBAL_AS(gB0s + j * 32),
                                     LDS_AS(lB + j * 8192 + t * 8), 16, 0, 0);
    __builtin_amdgcn_global_load_lds(GLOBAL_AS(gB1s + j * 32),
                                     LDS_AS(lB + j * 8192 + (t + 512) * 8), 16, 0, 0);
  }

  for (int kt = 0; kt < G8_NT - 3; ++kt) PHASE(kt, 1, "6");
  PHASE(G8_NT - 3, 0, "6");
  PHASE(G8_NT - 2, 0, "3");
  PHASE(G8_NT - 1, 0, "0");

#pragma unroll
  for (int mi = 0; mi < 4; ++mi) {
    int row = m0 + wm * 64 + mi * 16 + g * 4;
#pragma unroll
    for (int ni = 0; ni < 4; ++ni) {
      int col = n0 + wn * 64 + ni * 16 + lr;
#pragma unroll
      for (int r = 0; r < 4; ++r) {
        float v = acc[mi][ni][r];
        if (EPI == 0) {
          ((u16*)Cout)[(size_t)(row + r) * N + col] = f2b(v);
        } else {
          ((float*)Cout)[(size_t)(row + r) * N + col] = v + bias[col];
        }
      }
    }
  }
}

// ---------------- local attention ----------------
// qkv: (B*N, 2304) bf16 rows: [q(768) | k(768) | v(768)], within each: h*64+d
#define NTILE 128
#define ROWS 140  // NTILE + 2*6
#define LPAD 66

__global__ __launch_bounds__(128) void attn_kernel(const u16* __restrict__ qkv,
                                                   u16* __restrict__ attn) {
  const int nt = blockIdx.x, h = blockIdx.y, b = blockIdx.z;
  const int n0 = nt * NTILE;
  const int t = threadIdx.x;
  __shared__ u16 kl[ROWS * LPAD];
  __shared__ u16 vl[ROWS * LPAD];

  for (int i = t; i < 2 * ROWS * 8; i += 128) {
    int mat = i >= ROWS * 8;
    int j = mat ? i - ROWS * 8 : i;
    int r = j >> 3, c = j & 7;
    int grow = n0 - 6 + r;
    grow = grow < 0 ? 0 : (grow > 4095 ? 4095 : grow);
    const uint4 u =
        *(const uint4*)(qkv + (size_t)(b * 4096 + grow) * 2304 + (mat ? 1536 : 768) + h * 64 + c * 8);
    u16* dst = (mat ? vl : kl) + r * LPAD + c * 8;
    ((u32*)dst)[0] = u.x;
    ((u32*)dst)[1] = u.y;
    ((u32*)dst)[2] = u.z;
    ((u32*)dst)[3] = u.w;
  }
  __syncthreads();

  const int wv = t >> 6, l = t & 63;
  const int n = n0 + wv * 64 + l;
  const int lrow = wv * 64 + l;

  float qf[64];
  const u16* qp = qkv + (size_t)(b * 4096 + n) * 2304 + h * 64;
#pragma unroll
  for (int c = 0; c < 8; ++c) {
    uint4 u = *(const uint4*)(qp + c * 8);
    qf[c * 8 + 0] = blo(u.x); qf[c * 8 + 1] = bhi(u.x);
    qf[c * 8 + 2] = blo(u.y); qf[c * 8 + 3] = bhi(u.y);
    qf[c * 8 + 4] = blo(u.z); qf[c * 8 + 5] = bhi(u.z);
    qf[c * 8 + 6] = blo(u.w); qf[c * 8 + 7] = bhi(u.w);
  }

  float s[13];
#pragma unroll
  for (int w = 0; w < 13; ++w) s[w] = 0.f;
#pragma unroll
  for (int d2 = 0; d2 < 32; ++d2) {
    float q0 = qf[2 * d2], q1 = qf[2 * d2 + 1];
#pragma unroll
    for (int w = 0; w < 13; ++w) {
      u32 u = *(const u32*)(kl + (lrow + w) * LPAD + 2 * d2);
      s[w] += q0 * blo(u) + q1 * bhi(u);
    }
  }

#pragma unroll
  for (int w = 0; w < 13; ++w) {
    int nn = n - 6 + w;
    s[w] = (nn >= 0 && nn < 4096) ? s[w] * 0.125f : -1e30f;
  }
  float m = s[0];
#pragma unroll
  for (int w = 1; w < 13; ++w) m = fmaxf(m, s[w]);
  float sum = 0.f;
#pragma unroll
  for (int w = 0; w < 13; ++w) {
    float p = __expf(s[w] - m);
    s[w] = p;
    sum += p;
  }
  float inv = 1.0f / sum;

  float o[64];
#pragma unroll
  for (int d = 0; d < 64; ++d) o[d] = 0.f;
#pragma unroll
  for (int w = 0; w < 13; ++w) {
    float pw = s[w] * inv;
#pragma unroll
    for (int d2 = 0; d2 < 32; ++d2) {
      u32 u = *(const u32*)(vl + (lrow + w) * LPAD + 2 * d2);
      o[2 * d2] += pw * blo(u);
      o[2 * d2 + 1] += pw * bhi(u);
    }
  }

  u16* op = attn + (size_t)(b * 4096 + n) * 768 + h * 64;
#pragma unroll
  for (int c = 0; c < 8; ++c) {
    uint4 u;
    u.x = (u32)f2b(o[c * 8 + 0]) | ((u32)f2b(o[c * 8 + 1]) << 16);
    u.y = (u32)f2b(o[c * 8 + 2]) | ((u32)f2b(o[c * 8 + 3]) << 16);
    u.z = (u32)f2b(o[c * 8 + 4]) | ((u32)f2b(o[c * 8 + 5]) << 16);
    u.w = (u32)f2b(o[c * 8 + 6]) | ((u32)f2b(o[c * 8 + 7]) << 16);
    ((uint4*)op)[c] = u;
  }
}

extern "C" void kernel_launch(void* const* d_in, const int* in_sizes, int n_in,
                              void* d_out, int out_size, void* d_ws, size_t ws_size,
                              hipStream_t stream) {
  const float* x = (const float*)d_in[0];
  const float* w_qkv = (const float*)d_in[1];
  const float* w_proj = (const float*)d_in[2];
  const float* b_proj = (const float*)d_in[3];
  float* out = (float*)d_out;

  char* p = (char*)d_ws;
  u16* xb = (u16*)p;     p += (size_t)8192 * 768 * 2;
  u16* wqT = (u16*)p;    p += (size_t)2304 * 768 * 2;
  u16* wpT = (u16*)p;    p += (size_t)768 * 768 * 2;
  u16* qkvb = (u16*)p;   p += (size_t)8192 * 2304 * 2;
  u16* attnb = (u16*)p;  p += (size_t)8192 * 768 * 2;

  const int dynlds = 96 * 1024;
  hipFuncSetAttribute((const void*)gemm8p<0>, hipFuncAttributeMaxDynamicSharedMemorySize, dynlds);
  hipFuncSetAttribute((const void*)gemm8p<1>, hipFuncAttributeMaxDynamicSharedMemorySize, dynlds);

  conv_bf16<<<dim3(1024), dim3(256), 0, stream>>>(x, xb, 8192 * 768 / 4);
  transpose_conv<<<dim3(2304 / 32, 768 / 32), dim3(32, 8), 0, stream>>>(w_qkv, wqT, 768, 2304);
  transpose_conv<<<dim3(768 / 32, 768 / 32), dim3(32, 8), 0, stream>>>(w_proj, wpT, 768, 768);

  gemm8p<0><<<dim3(2304 / 256, 8192 / 128), dim3(512), dynlds, stream>>>(
      xb, wqT, (void*)qkvb, nullptr, 8192, 2304, 768);

  attn_kernel<<<dim3(4096 / NTILE, 12, 2), dim3(128), 0, stream>>>(qkvb, attnb);

  gemm8p<1><<<dim3(768 / 256, 8192 / 128), dim3(512), dynlds, stream>>>(
      attnb, wpT, (void*)out, b_proj, 8192, 768, 768);
}

// Round 4
// 179.169 us; speedup vs baseline: 1.1008x; 1.0590x over previous
//
#include <hip/hip_runtime.h>

typedef unsigned short u16;
typedef unsigned int u32;
typedef __attribute__((ext_vector_type(8))) short short8;
typedef __attribute__((ext_vector_type(4))) float f32x4;

#define GLOBAL_AS(p) (const __attribute__((address_space(1))) void*)(p)
#define LDS_AS(p) (__attribute__((address_space(3))) void*)(p)

__device__ __forceinline__ u16 f2b(float f) {
  u32 u = __float_as_uint(f);
  u32 r = (u + 0x7fffu + ((u >> 16) & 1u)) >> 16;
  return (u16)r;
}
__device__ __forceinline__ float blo(u32 u) { return __uint_as_float(u << 16); }
__device__ __forceinline__ float bhi(u32 u) { return __uint_as_float(u & 0xffff0000u); }

// ---------------- fp32 -> bf16 convert (x) ----------------
__global__ void conv_bf16(const float* __restrict__ in, u16* __restrict__ out, int n4) {
  int i = blockIdx.x * blockDim.x + threadIdx.x;
  int stride = gridDim.x * blockDim.x;
  for (; i < n4; i += stride) {
    float4 f = ((const float4*)in)[i];
    ushort4 u;
    u.x = f2b(f.x); u.y = f2b(f.y); u.z = f2b(f.z); u.w = f2b(f.w);
    ((ushort4*)out)[i] = u;
  }
}

// ---- fused weight transpose+convert: z=0 w_qkv(768x2304), z=1 w_proj(768x768) ----
__global__ void transpose_conv2(const float* __restrict__ w_qkv, u16* __restrict__ wqT,
                                const float* __restrict__ w_proj, u16* __restrict__ wpT) {
  __shared__ float tile[32][33];
  const int z = blockIdx.z;
  if (z && blockIdx.x >= 24) return;  // w_proj has only 768/32=24 col-blocks
  const float* in = z ? w_proj : w_qkv;
  u16* out = z ? wpT : wqT;
  const int Cc = z ? 768 : 2304;
  int c0 = blockIdx.x * 32, r0 = blockIdx.y * 32;
  int tx = threadIdx.x, ty = threadIdx.y;  // 32 x 8
#pragma unroll
  for (int i = 0; i < 32; i += 8)
    tile[ty + i][tx] = in[(size_t)(r0 + ty + i) * Cc + c0 + tx];
  __syncthreads();
#pragma unroll
  for (int i = 0; i < 32; i += 8)
    out[(size_t)(c0 + ty + i) * 768 + r0 + tx] = f2b(tile[tx][ty + i]);
}

// ---------------- GEMM: C = A(MxK) * Bt(NxK)^T, bf16 in, fp32 acc ----------------
// BM=128, BN=256, BK=32, K=768 (24 tiles), 512 threads = 8 waves (2M x 4N),
// per-wave output 64x64. 3-buffer LDS ring (72 KiB) -> 2 blocks/CU; depth-2
// prefetch, counted vmcnt(3), ONE barrier per K-tile, setprio on MFMA cluster.
// 16B-chunk swizzle chunk^=( (row>>1)&3 ) applied on staging source AND read.
// XCD-bijective block swizzle: 9 (or 3) consecutive logicals share an A-panel.

#define STAGE(KT, SB)                                                                    \
  do {                                                                                   \
    __builtin_amdgcn_global_load_lds(GLOBAL_AS(gAs + (KT) * 32),                         \
                                     LDS_AS(lA + (SB) * 4096 + t * 8), 16, 0, 0);        \
    __builtin_amdgcn_global_load_lds(GLOBAL_AS(gB0s + (KT) * 32),                        \
                                     LDS_AS(lB + (SB) * 8192 + t * 8), 16, 0, 0);        \
    __builtin_amdgcn_global_load_lds(GLOBAL_AS(gB1s + (KT) * 32),                        \
                                     LDS_AS(lB + (SB) * 8192 + (t + 512) * 8), 16, 0, 0);\
  } while (0)

#define ITER(KT, CB, SB, DOSTAGE, VM)                                                    \
  do {                                                                                   \
    asm volatile("s_waitcnt vmcnt(" VM ")" ::: "memory");                                \
    __builtin_amdgcn_s_barrier();                                                        \
    asm volatile("" ::: "memory");                                                       \
    if (DOSTAGE) STAGE((KT) + 2, SB);                                                    \
    const u16* pa_ = lA + (CB) * 4096;                                                   \
    const u16* pb_ = lB + (CB) * 8192;                                                   \
    short8 af0 = *(const short8*)(pa_ + aoff0);                                          \
    short8 af1 = *(const short8*)(pa_ + aoff1);                                          \
    short8 af2 = *(const short8*)(pa_ + aoff2);                                          \
    short8 af3 = *(const short8*)(pa_ + aoff3);                                          \
    short8 bf0 = *(const short8*)(pb_ + boff0);                                          \
    short8 bf1 = *(const short8*)(pb_ + boff1);                                          \
    short8 bf2 = *(const short8*)(pb_ + boff2);                                          \
    short8 bf3 = *(const short8*)(pb_ + boff3);                                          \
    __builtin_amdgcn_s_setprio(1);                                                       \
    acc[0][0] = __builtin_amdgcn_mfma_f32_16x16x32_bf16(af0, bf0, acc[0][0], 0, 0, 0);   \
    acc[0][1] = __builtin_amdgcn_mfma_f32_16x16x32_bf16(af0, bf1, acc[0][1], 0, 0, 0);   \
    acc[0][2] = __builtin_amdgcn_mfma_f32_16x16x32_bf16(af0, bf2, acc[0][2], 0, 0, 0);   \
    acc[0][3] = __builtin_amdgcn_mfma_f32_16x16x32_bf16(af0, bf3, acc[0][3], 0, 0, 0);   \
    acc[1][0] = __builtin_amdgcn_mfma_f32_16x16x32_bf16(af1, bf0, acc[1][0], 0, 0, 0);   \
    acc[1][1] = __builtin_amdgcn_mfma_f32_16x16x32_bf16(af1, bf1, acc[1][1], 0, 0, 0);   \
    acc[1][2] = __builtin_amdgcn_mfma_f32_16x16x32_bf16(af1, bf2, acc[1][2], 0, 0, 0);   \
    acc[1][3] = __builtin_amdgcn_mfma_f32_16x16x32_bf16(af1, bf3, acc[1][3], 0, 0, 0);   \
    acc[2][0] = __builtin_amdgcn_mfma_f32_16x16x32_bf16(af2, bf0, acc[2][0], 0, 0, 0);   \
    acc[2][1] = __builtin_amdgcn_mfma_f32_16x16x32_bf16(af2, bf1, acc[2][1], 0, 0, 0);   \
    acc[2][2] = __builtin_amdgcn_mfma_f32_16x16x32_bf16(af2, bf2, acc[2][2], 0, 0, 0);   \
    acc[2][3] = __builtin_amdgcn_mfma_f32_16x16x32_bf16(af2, bf3, acc[2][3], 0, 0, 0);   \
    acc[3][0] = __builtin_amdgcn_mfma_f32_16x16x32_bf16(af3, bf0, acc[3][0], 0, 0, 0);   \
    acc[3][1] = __builtin_amdgcn_mfma_f32_16x16x32_bf16(af3, bf1, acc[3][1], 0, 0, 0);   \
    acc[3][2] = __builtin_amdgcn_mfma_f32_16x16x32_bf16(af3, bf2, acc[3][2], 0, 0, 0);   \
    acc[3][3] = __builtin_amdgcn_mfma_f32_16x16x32_bf16(af3, bf3, acc[3][3], 0, 0, 0);   \
    __builtin_amdgcn_s_setprio(0);                                                       \
    asm volatile("" ::: "memory");                                                       \
  } while (0)

template <int EPI>
__global__ __launch_bounds__(512, 4) void gemm3r(
    const u16* __restrict__ A, const u16* __restrict__ Bt, void* __restrict__ Cout,
    const float* __restrict__ bias, int M, int N, int K, int NX) {
  extern __shared__ u16 sm[];
  u16* lA = sm;             // 3 bufs x 128x32 u16 = 24 KiB
  u16* lB = sm + 3 * 4096;  // 3 bufs x 256x32 u16 = 48 KiB
  const int t = threadIdx.x;
  // XCD-bijective swizzle (nwg % 8 == 0): consecutive logicals share A-panel
  const int nwg = gridDim.x;
  const int logical = (blockIdx.x & 7) * (nwg >> 3) + (blockIdx.x >> 3);
  const int m0 = (logical / NX) * 128;
  const int n0 = (logical % NX) * 256;
  const int wv = t >> 6, l = t & 63;
  const int wm = wv >> 2, wn = wv & 3;
  const int lr = l & 15, g = l >> 4;

  // staging source (pre-swizzled): chunk id -> row id>>2, src chunk (id&3)^((row>>1)&3)
  const int ra = t >> 2;
  const int ca = (t & 3) ^ ((ra >> 1) & 3);
  const u16* gAs = A + (size_t)(m0 + ra) * K + ca * 8;
  const u16* gB0s = Bt + (size_t)(n0 + ra) * K + ca * 8;
  const u16* gB1s = Bt + (size_t)(n0 + ra + 128) * K + ca * 8;  // +128 keeps swizzle bits

  // fragment ds_read offsets (u16 units): row r -> r*32 + (g^((lr>>1)&3))*8
  const int cswz = (g ^ ((lr >> 1) & 3)) * 8;
  const int ar = wm * 64 + lr;
  const int br = wn * 64 + lr;
  const int aoff0 = (ar + 0) * 32 + cswz, aoff1 = (ar + 16) * 32 + cswz;
  const int aoff2 = (ar + 32) * 32 + cswz, aoff3 = (ar + 48) * 32 + cswz;
  const int boff0 = (br + 0) * 32 + cswz, boff1 = (br + 16) * 32 + cswz;
  const int boff2 = (br + 32) * 32 + cswz, boff3 = (br + 48) * 32 + cswz;

  f32x4 acc[4][4] = {};

  STAGE(0, 0);
  STAGE(1, 1);
  // K=768 -> 24 tiles; main: kt=0..20 (x3 unroll), tail 21(stage 23), 22, 23
  for (int j = 0; j < 7; ++j) {
    const int kt = j * 3;
    ITER(kt + 0, 0, 2, 1, "3");
    ITER(kt + 1, 1, 0, 1, "3");
    ITER(kt + 2, 2, 1, 1, "3");
  }
  ITER(21, 0, 2, 1, "3");
  ITER(22, 1, 2, 0, "3");
  ITER(23, 2, 2, 0, "0");

#pragma unroll
  for (int mi = 0; mi < 4; ++mi) {
    int row = m0 + wm * 64 + mi * 16 + g * 4;
#pragma unroll
    for (int ni = 0; ni < 4; ++ni) {
      int col = n0 + wn * 64 + ni * 16 + lr;
#pragma unroll
      for (int r = 0; r < 4; ++r) {
        float v = acc[mi][ni][r];
        if (EPI == 0) {
          ((u16*)Cout)[(size_t)(row + r) * N + col] = f2b(v);
        } else {
          ((float*)Cout)[(size_t)(row + r) * N + col] = v + bias[col];
        }
      }
    }
  }
}

// ---------------- local attention ----------------
// qkv: (B*N, 2304) bf16 rows: [q(768) | k(768) | v(768)], within each: h*64+d
#define NTILE 128
#define ROWS 140  // NTILE + 2*6
#define LPAD 66

__global__ __launch_bounds__(128) void attn_kernel(const u16* __restrict__ qkv,
                                                   u16* __restrict__ attn) {
  const int nt = blockIdx.x, h = blockIdx.y, b = blockIdx.z;
  const int n0 = nt * NTILE;
  const int t = threadIdx.x;
  __shared__ u16 kl[ROWS * LPAD];
  __shared__ u16 vl[ROWS * LPAD];

  for (int i = t; i < 2 * ROWS * 8; i += 128) {
    int mat = i >= ROWS * 8;
    int j = mat ? i - ROWS * 8 : i;
    int r = j >> 3, c = j & 7;
    int grow = n0 - 6 + r;
    grow = grow < 0 ? 0 : (grow > 4095 ? 4095 : grow);
    const uint4 u =
        *(const uint4*)(qkv + (size_t)(b * 4096 + grow) * 2304 + (mat ? 1536 : 768) + h * 64 + c * 8);
    u16* dst = (mat ? vl : kl) + r * LPAD + c * 8;
    ((u32*)dst)[0] = u.x;
    ((u32*)dst)[1] = u.y;
    ((u32*)dst)[2] = u.z;
    ((u32*)dst)[3] = u.w;
  }
  __syncthreads();

  const int wv = t >> 6, l = t & 63;
  const int n = n0 + wv * 64 + l;
  const int lrow = wv * 64 + l;

  float qf[64];
  const u16* qp = qkv + (size_t)(b * 4096 + n) * 2304 + h * 64;
#pragma unroll
  for (int c = 0; c < 8; ++c) {
    uint4 u = *(const uint4*)(qp + c * 8);
    qf[c * 8 + 0] = blo(u.x); qf[c * 8 + 1] = bhi(u.x);
    qf[c * 8 + 2] = blo(u.y); qf[c * 8 + 3] = bhi(u.y);
    qf[c * 8 + 4] = blo(u.z); qf[c * 8 + 5] = bhi(u.z);
    qf[c * 8 + 6] = blo(u.w); qf[c * 8 + 7] = bhi(u.w);
  }

  float s[13];
#pragma unroll
  for (int w = 0; w < 13; ++w) s[w] = 0.f;
#pragma unroll
  for (int d2 = 0; d2 < 32; ++d2) {
    float q0 = qf[2 * d2], q1 = qf[2 * d2 + 1];
#pragma unroll
    for (int w = 0; w < 13; ++w) {
      u32 u = *(const u32*)(kl + (lrow + w) * LPAD + 2 * d2);
      s[w] += q0 * blo(u) + q1 * bhi(u);
    }
  }

#pragma unroll
  for (int w = 0; w < 13; ++w) {
    int nn = n - 6 + w;
    s[w] = (nn >= 0 && nn < 4096) ? s[w] * 0.125f : -1e30f;
  }
  float m = s[0];
#pragma unroll
  for (int w = 1; w < 13; ++w) m = fmaxf(m, s[w]);
  float sum = 0.f;
#pragma unroll
  for (int w = 0; w < 13; ++w) {
    float p = __expf(s[w] - m);
    s[w] = p;
    sum += p;
  }
  float inv = 1.0f / sum;

  float o[64];
#pragma unroll
  for (int d = 0; d < 64; ++d) o[d] = 0.f;
#pragma unroll
  for (int w = 0; w < 13; ++w) {
    float pw = s[w] * inv;
#pragma unroll
    for (int d2 = 0; d2 < 32; ++d2) {
      u32 u = *(const u32*)(vl + (lrow + w) * LPAD + 2 * d2);
      o[2 * d2] += pw * blo(u);
      o[2 * d2 + 1] += pw * bhi(u);
    }
  }

  u16* op = attn + (size_t)(b * 4096 + n) * 768 + h * 64;
#pragma unroll
  for (int c = 0; c < 8; ++c) {
    uint4 u;
    u.x = (u32)f2b(o[c * 8 + 0]) | ((u32)f2b(o[c * 8 + 1]) << 16);
    u.y = (u32)f2b(o[c * 8 + 2]) | ((u32)f2b(o[c * 8 + 3]) << 16);
    u.z = (u32)f2b(o[c * 8 + 4]) | ((u32)f2b(o[c * 8 + 5]) << 16);
    u.w = (u32)f2b(o[c * 8 + 6]) | ((u32)f2b(o[c * 8 + 7]) << 16);
    ((uint4*)op)[c] = u;
  }
}

extern "C" void kernel_launch(void* const* d_in, const int* in_sizes, int n_in,
                              void* d_out, int out_size, void* d_ws, size_t ws_size,
                              hipStream_t stream) {
  const float* x = (const float*)d_in[0];
  const float* w_qkv = (const float*)d_in[1];
  const float* w_proj = (const float*)d_in[2];
  const float* b_proj = (const float*)d_in[3];
  float* out = (float*)d_out;

  char* p = (char*)d_ws;
  u16* xb = (u16*)p;     p += (size_t)8192 * 768 * 2;
  u16* wqT = (u16*)p;    p += (size_t)2304 * 768 * 2;
  u16* wpT = (u16*)p;    p += (size_t)768 * 768 * 2;
  u16* qkvb = (u16*)p;   p += (size_t)8192 * 2304 * 2;
  u16* attnb = (u16*)p;  p += (size_t)8192 * 768 * 2;

  const int dynlds = 72 * 1024;
  hipFuncSetAttribute((const void*)gemm3r<0>, hipFuncAttributeMaxDynamicSharedMemorySize, dynlds);
  hipFuncSetAttribute((const void*)gemm3r<1>, hipFuncAttributeMaxDynamicSharedMemorySize, dynlds);

  conv_bf16<<<dim3(1024), dim3(256), 0, stream>>>(x, xb, 8192 * 768 / 4);
  transpose_conv2<<<dim3(72, 24, 2), dim3(32, 8), 0, stream>>>(w_qkv, wqT, w_proj, wpT);

  gemm3r<0><<<dim3(9 * 64), dim3(512), dynlds, stream>>>(
      xb, wqT, (void*)qkvb, nullptr, 8192, 2304, 768, 9);

  attn_kernel<<<dim3(4096 / NTILE, 12, 2), dim3(128), 0, stream>>>(qkvb, attnb);

  gemm3r<1><<<dim3(3 * 64), dim3(512), dynlds, stream>>>(
      attnb, wpT, (void*)out, b_proj, 8192, 768, 768, 3);
}

// Round 8
// 178.729 us; speedup vs baseline: 1.1035x; 1.0025x over previous
//
#include <hip/hip_runtime.h>

typedef unsigned short u16;
typedef unsigned int u32;
typedef __attribute__((ext_vector_type(8))) short short8;
typedef __attribute__((ext_vector_type(4))) float f32x4;

#define GLOBAL_AS(p) (const __attribute__((address_space(1))) void*)(p)
#define LDS_AS(p) (__attribute__((address_space(3))) void*)(p)

__device__ __forceinline__ u16 f2b(float f) {
  u32 u = __float_as_uint(f);
  u32 r = (u + 0x7fffu + ((u >> 16) & 1u)) >> 16;
  return (u16)r;
}
__device__ __forceinline__ float blo(u32 u) { return __uint_as_float(u << 16); }
__device__ __forceinline__ float bhi(u32 u) { return __uint_as_float(u & 0xffff0000u); }

// ---------------- fp32 -> bf16 convert (x) ----------------
__global__ void conv_bf16(const float* __restrict__ in, u16* __restrict__ out, int n4) {
  int i = blockIdx.x * blockDim.x + threadIdx.x;
  int stride = gridDim.x * blockDim.x;
  for (; i < n4; i += stride) {
    float4 f = ((const float4*)in)[i];
    ushort4 u;
    u.x = f2b(f.x); u.y = f2b(f.y); u.z = f2b(f.z); u.w = f2b(f.w);
    ((ushort4*)out)[i] = u;
  }
}

// ---- fused weight transpose+convert: z=0 w_qkv(768x2304), z=1 w_proj(768x768) ----
__global__ void transpose_conv2(const float* __restrict__ w_qkv, u16* __restrict__ wqT,
                                const float* __restrict__ w_proj, u16* __restrict__ wpT) {
  __shared__ float tile[32][33];
  const int z = blockIdx.z;
  if (z && blockIdx.x >= 24) return;
  const float* in = z ? w_proj : w_qkv;
  u16* out = z ? wpT : wqT;
  const int Cc = z ? 768 : 2304;
  int c0 = blockIdx.x * 32, r0 = blockIdx.y * 32;
  int tx = threadIdx.x, ty = threadIdx.y;  // 32 x 8
#pragma unroll
  for (int i = 0; i < 32; i += 8)
    tile[ty + i][tx] = in[(size_t)(r0 + ty + i) * Cc + c0 + tx];
  __syncthreads();
#pragma unroll
  for (int i = 0; i < 32; i += 8)
    out[(size_t)(c0 + ty + i) * 768 + r0 + tx] = f2b(tile[tx][ty + i]);
}

// ---------------- GEMM: C = A(MxK) * Bt(NxK)^T, bf16 in, fp32 acc ----------------
// BM=128, BN=256, BK=64, K=768 (12 tiles), 512 threads = 8 waves (2M x 4N),
// per-wave output 64x64, 32 MFMA per K-iter. 3-buffer LDS ring (144 KiB),
// depth-2 prefetch, counted vmcnt(6), ONE barrier per K-iter, setprio on MFMA.
// Swizzle: 16B-chunk' = chunk ^ (row&7), applied on staging source AND ds_read.
// XCD-bijective block swizzle (nwg%8==0): consecutive logicals share A-panel.

#define STAGE64(KT, SB)                                                                   \
  do {                                                                                    \
    __builtin_amdgcn_global_load_lds(GLOBAL_AS(gA0 + (KT) * 64),                          \
                                     LDS_AS(lA + (SB) * 8192 + t * 8), 16, 0, 0);         \
    __builtin_amdgcn_global_load_lds(GLOBAL_AS(gA1 + (KT) * 64),                          \
                                     LDS_AS(lA + (SB) * 8192 + (t + 512) * 8), 16, 0, 0); \
    __builtin_amdgcn_global_load_lds(GLOBAL_AS(gB0 + (KT) * 64),                          \
                                     LDS_AS(lB + (SB) * 16384 + t * 8), 16, 0, 0);        \
    __builtin_amdgcn_global_load_lds(GLOBAL_AS(gB1 + (KT) * 64),                          \
                                     LDS_AS(lB + (SB) * 16384 + (t + 512) * 8), 16, 0, 0);\
    __builtin_amdgcn_global_load_lds(GLOBAL_AS(gB2 + (KT) * 64),                          \
                                     LDS_AS(lB + (SB) * 16384 + (t + 1024) * 8), 16, 0, 0);\
    __builtin_amdgcn_global_load_lds(GLOBAL_AS(gB3 + (KT) * 64),                          \
                                     LDS_AS(lB + (SB) * 16384 + (t + 1536) * 8), 16, 0, 0);\
  } while (0)

#define MFMA16(AK0, AK1, AK2, AK3, BK0, BK1, BK2, BK3)                                   \
  do {                                                                                   \
    __builtin_amdgcn_s_setprio(1);                                                       \
    acc[0][0] = __builtin_amdgcn_mfma_f32_16x16x32_bf16(AK0, BK0, acc[0][0], 0, 0, 0);   \
    acc[0][1] = __builtin_amdgcn_mfma_f32_16x16x32_bf16(AK0, BK1, acc[0][1], 0, 0, 0);   \
    acc[0][2] = __builtin_amdgcn_mfma_f32_16x16x32_bf16(AK0, BK2, acc[0][2], 0, 0, 0);   \
    acc[0][3] = __builtin_amdgcn_mfma_f32_16x16x32_bf16(AK0, BK3, acc[0][3], 0, 0, 0);   \
    acc[1][0] = __builtin_amdgcn_mfma_f32_16x16x32_bf16(AK1, BK0, acc[1][0], 0, 0, 0);   \
    acc[1][1] = __builtin_amdgcn_mfma_f32_16x16x32_bf16(AK1, BK1, acc[1][1], 0, 0, 0);   \
    acc[1][2] = __builtin_amdgcn_mfma_f32_16x16x32_bf16(AK1, BK2, acc[1][2], 0, 0, 0);   \
    acc[1][3] = __builtin_amdgcn_mfma_f32_16x16x32_bf16(AK1, BK3, acc[1][3], 0, 0, 0);   \
    acc[2][0] = __builtin_amdgcn_mfma_f32_16x16x32_bf16(AK2, BK0, acc[2][0], 0, 0, 0);   \
    acc[2][1] = __builtin_amdgcn_mfma_f32_16x16x32_bf16(AK2, BK1, acc[2][1], 0, 0, 0);   \
    acc[2][2] = __builtin_amdgcn_mfma_f32_16x16x32_bf16(AK2, BK2, acc[2][2], 0, 0, 0);   \
    acc[2][3] = __builtin_amdgcn_mfma_f32_16x16x32_bf16(AK2, BK3, acc[2][3], 0, 0, 0);   \
    acc[3][0] = __builtin_amdgcn_mfma_f32_16x16x32_bf16(AK3, BK0, acc[3][0], 0, 0, 0);   \
    acc[3][1] = __builtin_amdgcn_mfma_f32_16x16x32_bf16(AK3, BK1, acc[3][1], 0, 0, 0);   \
    acc[3][2] = __builtin_amdgcn_mfma_f32_16x16x32_bf16(AK3, BK2, acc[3][2], 0, 0, 0);   \
    acc[3][3] = __builtin_amdgcn_mfma_f32_16x16x32_bf16(AK3, BK3, acc[3][3], 0, 0, 0);   \
    __builtin_amdgcn_s_setprio(0);                                                       \
  } while (0)

#define ITER64(KT, CB, SB, DOSTAGE, VM)                                                  \
  do {                                                                                   \
    asm volatile("s_waitcnt vmcnt(" VM ")" ::: "memory");                                \
    __builtin_amdgcn_s_barrier();                                                        \
    asm volatile("" ::: "memory");                                                       \
    if (DOSTAGE) STAGE64((KT) + 2, SB);                                                  \
    const u16* pa_ = lA + (CB) * 8192;                                                   \
    const u16* pb_ = lB + (CB) * 16384;                                                  \
    short8 a0 = *(const short8*)(pa_ + arow0 + cs0);                                     \
    short8 a1 = *(const short8*)(pa_ + arow1 + cs0);                                     \
    short8 a2 = *(const short8*)(pa_ + arow2 + cs0);                                     \
    short8 a3 = *(const short8*)(pa_ + arow3 + cs0);                                     \
    short8 b0 = *(const short8*)(pb_ + brow0 + cs0);                                     \
    short8 b1 = *(const short8*)(pb_ + brow1 + cs0);                                     \
    short8 b2 = *(const short8*)(pb_ + brow2 + cs0);                                     \
    short8 b3 = *(const short8*)(pb_ + brow3 + cs0);                                     \
    MFMA16(a0, a1, a2, a3, b0, b1, b2, b3);                                              \
    short8 c0v = *(const short8*)(pa_ + arow0 + cs1);                                    \
    short8 c1v = *(const short8*)(pa_ + arow1 + cs1);                                    \
    short8 c2v = *(const short8*)(pa_ + arow2 + cs1);                                    \
    short8 c3v = *(const short8*)(pa_ + arow3 + cs1);                                    \
    short8 d0v = *(const short8*)(pb_ + brow0 + cs1);                                    \
    short8 d1v = *(const short8*)(pb_ + brow1 + cs1);                                    \
    short8 d2v = *(const short8*)(pb_ + brow2 + cs1);                                    \
    short8 d3v = *(const short8*)(pb_ + brow3 + cs1);                                    \
    MFMA16(c0v, c1v, c2v, c3v, d0v, d1v, d2v, d3v);                                      \
  } while (0)

template <int EPI>
__global__ __launch_bounds__(512, 2) void gemm64(
    const u16* __restrict__ A, const u16* __restrict__ Bt, void* __restrict__ Cout,
    const float* __restrict__ bias, int M, int N, int K, int NX) {
  extern __shared__ u16 sm[];
  u16* lA = sm;              // 3 bufs x 128x64 u16 = 48 KiB
  u16* lB = sm + 3 * 8192;   // 3 bufs x 256x64 u16 = 96 KiB
  const int t = threadIdx.x;
  const int nwg = gridDim.x;
  const int logical = (blockIdx.x & 7) * (nwg >> 3) + (blockIdx.x >> 3);
  const int m0 = (logical / NX) * 128;
  const int n0 = (logical % NX) * 256;
  const int wv = t >> 6, l = t & 63;
  const int wm = wv >> 2, wn = wv & 3;
  const int lr = l & 15, g = l >> 4;

  // staging source (pre-swizzled): chunk c -> row c>>3, src chunk (c&7)^(row&7)
  const int ra = t >> 3;
  const int ca = (t & 7) ^ (ra & 7);
  const u16* gA0 = A + (size_t)(m0 + ra) * K + ca * 8;
  const u16* gA1 = A + (size_t)(m0 + ra + 64) * K + ca * 8;
  const u16* gB0 = Bt + (size_t)(n0 + ra) * K + ca * 8;
  const u16* gB1 = Bt + (size_t)(n0 + ra + 64) * K + ca * 8;
  const u16* gB2 = Bt + (size_t)(n0 + ra + 128) * K + ca * 8;
  const u16* gB3 = Bt + (size_t)(n0 + ra + 192) * K + ca * 8;

  // fragment ds_read offsets (u16 units): row r, k-chunk kc -> r*64 + (kc^(r&7))*8
  const int cs0 = ((g + 0) ^ (lr & 7)) * 8;
  const int cs1 = ((g + 4) ^ (lr & 7)) * 8;
  const int arow0 = (wm * 64 + lr + 0) * 64, arow1 = (wm * 64 + lr + 16) * 64;
  const int arow2 = (wm * 64 + lr + 32) * 64, arow3 = (wm * 64 + lr + 48) * 64;
  const int brow0 = (wn * 64 + lr + 0) * 64, brow1 = (wn * 64 + lr + 16) * 64;
  const int brow2 = (wn * 64 + lr + 32) * 64, brow3 = (wn * 64 + lr + 48) * 64;

  f32x4 acc[4][4] = {};

  STAGE64(0, 0);
  STAGE64(1, 1);
  // K=768 -> 12 tiles. kt=0..8 (x3 unroll), 9 (stage 11), tail 10, 11.
  for (int j = 0; j < 3; ++j) {
    const int kt = j * 3;
    ITER64(kt + 0, 0, 2, 1, "6");
    ITER64(kt + 1, 1, 0, 1, "6");
    ITER64(kt + 2, 2, 1, 1, "6");
  }
  ITER64(9, 0, 2, 1, "6");
  ITER64(10, 1, 2, 0, "6");
  ITER64(11, 2, 2, 0, "0");

#pragma unroll
  for (int mi = 0; mi < 4; ++mi) {
    int row = m0 + wm * 64 + mi * 16 + g * 4;
#pragma unroll
    for (int ni = 0; ni < 4; ++ni) {
      int col = n0 + wn * 64 + ni * 16 + lr;
#pragma unroll
      for (int r = 0; r < 4; ++r) {
        float v = acc[mi][ni][r];
        if (EPI == 0) {
          ((u16*)Cout)[(size_t)(row + r) * N + col] = f2b(v);
        } else {
          ((float*)Cout)[(size_t)(row + r) * N + col] = v + bias[col];
        }
      }
    }
  }
}

// ---------------- local attention ----------------
// qkv: (B*N, 2304) bf16 rows: [q(768) | k(768) | v(768)], within each: h*64+d
#define NTILE 128
#define ROWS 140  // NTILE + 2*6
#define LPAD 66

__global__ __launch_bounds__(128) void attn_kernel(const u16* __restrict__ qkv,
                                                   u16* __restrict__ attn) {
  const int nt = blockIdx.x, h = blockIdx.y, b = blockIdx.z;
  const int n0 = nt * NTILE;
  const int t = threadIdx.x;
  __shared__ u16 kl[ROWS * LPAD];
  __shared__ u16 vl[ROWS * LPAD];

  for (int i = t; i < 2 * ROWS * 8; i += 128) {
    int mat = i >= ROWS * 8;
    int j = mat ? i - ROWS * 8 : i;
    int r = j >> 3, c = j & 7;
    int grow = n0 - 6 + r;
    grow = grow < 0 ? 0 : (grow > 4095 ? 4095 : grow);
    const uint4 u =
        *(const uint4*)(qkv + (size_t)(b * 4096 + grow) * 2304 + (mat ? 1536 : 768) + h * 64 + c * 8);
    u16* dst = (mat ? vl : kl) + r * LPAD + c * 8;
    ((u32*)dst)[0] = u.x;
    ((u32*)dst)[1] = u.y;
    ((u32*)dst)[2] = u.z;
    ((u32*)dst)[3] = u.w;
  }
  __syncthreads();

  const int wv = t >> 6, l = t & 63;
  const int n = n0 + wv * 64 + l;
  const int lrow = wv * 64 + l;

  float qf[64];
  const u16* qp = qkv + (size_t)(b * 4096 + n) * 2304 + h * 64;
#pragma unroll
  for (int c = 0; c < 8; ++c) {
    uint4 u = *(const uint4*)(qp + c * 8);
    qf[c * 8 + 0] = blo(u.x); qf[c * 8 + 1] = bhi(u.x);
    qf[c * 8 + 2] = blo(u.y); qf[c * 8 + 3] = bhi(u.y);
    qf[c * 8 + 4] = blo(u.z); qf[c * 8 + 5] = bhi(u.z);
    qf[c * 8 + 6] = blo(u.w); qf[c * 8 + 7] = bhi(u.w);
  }

  float s[13];
#pragma unroll
  for (int w = 0; w < 13; ++w) s[w] = 0.f;
#pragma unroll
  for (int d2 = 0; d2 < 32; ++d2) {
    float q0 = qf[2 * d2], q1 = qf[2 * d2 + 1];
#pragma unroll
    for (int w = 0; w < 13; ++w) {
      u32 u = *(const u32*)(kl + (lrow + w) * LPAD + 2 * d2);
      s[w] += q0 * blo(u) + q1 * bhi(u);
    }
  }

#pragma unroll
  for (int w = 0; w < 13; ++w) {
    int nn = n - 6 + w;
    s[w] = (nn >= 0 && nn < 4096) ? s[w] * 0.125f : -1e30f;
  }
  float m = s[0];
#pragma unroll
  for (int w = 1; w < 13; ++w) m = fmaxf(m, s[w]);
  float sum = 0.f;
#pragma unroll
  for (int w = 0; w < 13; ++w) {
    float p = __expf(s[w] - m);
    s[w] = p;
    sum += p;
  }
  float inv = 1.0f / sum;

  float o[64];
#pragma unroll
  for (int d = 0; d < 64; ++d) o[d] = 0.f;
#pragma unroll
  for (int w = 0; w < 13; ++w) {
    float pw = s[w] * inv;
#pragma unroll
    for (int d2 = 0; d2 < 32; ++d2) {
      u32 u = *(const u32*)(vl + (lrow + w) * LPAD + 2 * d2);
      o[2 * d2] += pw * blo(u);
      o[2 * d2 + 1] += pw * bhi(u);
    }
  }

  u16* op = attn + (size_t)(b * 4096 + n) * 768 + h * 64;
#pragma unroll
  for (int c = 0; c < 8; ++c) {
    uint4 u;
    u.x = (u32)f2b(o[c * 8 + 0]) | ((u32)f2b(o[c * 8 + 1]) << 16);
    u.y = (u32)f2b(o[c * 8 + 2]) | ((u32)f2b(o[c * 8 + 3]) << 16);
    u.z = (u32)f2b(o[c * 8 + 4]) | ((u32)f2b(o[c * 8 + 5]) << 16);
    u.w = (u32)f2b(o[c * 8 + 6]) | ((u32)f2b(o[c * 8 + 7]) << 16);
    ((uint4*)op)[c] = u;
  }
}

extern "C" void kernel_launch(void* const* d_in, const int* in_sizes, int n_in,
                              void* d_out, int out_size, void* d_ws, size_t ws_size,
                              hipStream_t stream) {
  const float* x = (const float*)d_in[0];
  const float* w_qkv = (const float*)d_in[1];
  const float* w_proj = (const float*)d_in[2];
  const float* b_proj = (const float*)d_in[3];
  float* out = (float*)d_out;

  char* p = (char*)d_ws;
  u16* xb = (u16*)p;     p += (size_t)8192 * 768 * 2;
  u16* wqT = (u16*)p;    p += (size_t)2304 * 768 * 2;
  u16* wpT = (u16*)p;    p += (size_t)768 * 768 * 2;
  u16* qkvb = (u16*)p;   p += (size_t)8192 * 2304 * 2;
  u16* attnb = (u16*)p;  p += (size_t)8192 * 768 * 2;

  const int dynlds = 144 * 1024;
  hipFuncSetAttribute((const void*)gemm64<0>, hipFuncAttributeMaxDynamicSharedMemorySize, dynlds);
  hipFuncSetAttribute((const void*)gemm64<1>, hipFuncAttributeMaxDynamicSharedMemorySize, dynlds);

  conv_bf16<<<dim3(2048), dim3(256), 0, stream>>>(x, xb, 8192 * 768 / 4);
  transpose_conv2<<<dim3(72, 24, 2), dim3(32, 8), 0, stream>>>(w_qkv, wqT, w_proj, wpT);

  gemm64<0><<<dim3(9 * 64), dim3(512), dynlds, stream>>>(
      xb, wqT, (void*)qkvb, nullptr, 8192, 2304, 768, 9);

  attn_kernel<<<dim3(4096 / NTILE, 12, 2), dim3(128), 0, stream>>>(qkvb, attnb);

  gemm64<1><<<dim3(3 * 64), dim3(512), dynlds, stream>>>(
      attnb, wpT, (void*)out, b_proj, 8192, 768, 768, 3);
}

// Round 9
// 169.966 us; speedup vs baseline: 1.1604x; 1.0516x over previous
//
#include <hip/hip_runtime.h>

typedef unsigned short u16;
typedef unsigned int u32;
typedef __attribute__((ext_vector_type(8))) short short8;
typedef __attribute__((ext_vector_type(4))) float f32x4;

#define GLOBAL_AS(p) (const __attribute__((address_space(1))) void*)(p)
#define LDS_AS(p) (__attribute__((address_space(3))) void*)(p)

__device__ __forceinline__ u16 f2b(float f) {
  u32 u = __float_as_uint(f);
  u32 r = (u + 0x7fffu + ((u >> 16) & 1u)) >> 16;
  return (u16)r;
}
__device__ __forceinline__ float blo(u32 u) { return __uint_as_float(u << 16); }
__device__ __forceinline__ float bhi(u32 u) { return __uint_as_float(u & 0xffff0000u); }

// ---------------- fp32 -> bf16 convert (x) ----------------
__global__ void conv_bf16(const float* __restrict__ in, u16* __restrict__ out, int n4) {
  int i = blockIdx.x * blockDim.x + threadIdx.x;
  int stride = gridDim.x * blockDim.x;
  for (; i < n4; i += stride) {
    float4 f = ((const float4*)in)[i];
    ushort4 u;
    u.x = f2b(f.x); u.y = f2b(f.y); u.z = f2b(f.z); u.w = f2b(f.w);
    ((ushort4*)out)[i] = u;
  }
}

// ---- fused weight transpose+convert: z=0 w_qkv(768x2304), z=1 w_proj(768x768) ----
__global__ void transpose_conv2(const float* __restrict__ w_qkv, u16* __restrict__ wqT,
                                const float* __restrict__ w_proj, u16* __restrict__ wpT) {
  __shared__ float tile[32][33];
  const int z = blockIdx.z;
  if (z && blockIdx.x >= 24) return;
  const float* in = z ? w_proj : w_qkv;
  u16* out = z ? wpT : wqT;
  const int Cc = z ? 768 : 2304;
  int c0 = blockIdx.x * 32, r0 = blockIdx.y * 32;
  int tx = threadIdx.x, ty = threadIdx.y;  // 32 x 8
#pragma unroll
  for (int i = 0; i < 32; i += 8)
    tile[ty + i][tx] = in[(size_t)(r0 + ty + i) * Cc + c0 + tx];
  __syncthreads();
#pragma unroll
  for (int i = 0; i < 32; i += 8)
    out[(size_t)(c0 + ty + i) * 768 + r0 + tx] = f2b(tile[tx][ty + i]);
}

// ---------------- GEMM: C = A(MxK) * Bt(NxK)^T, bf16 in, fp32 acc ----------------
// BM=256, BN=NFRAG*16 (144 or 96), BK=64, K=768 (12 tiles). 512 threads = 8
// waves, wave wv owns rows [wv*32, wv*32+32) x all BN cols: acc = 2 x NFRAG
// f32x4 frags. 3-buffer LDS ring, depth-2 prefetch, counted per-wave vmcnt,
// ONE barrier per K-iter, setprio on MFMA. Swizzle: 16B-chunk' = chunk^(row&7)
// on BOTH staging source and ds_read. Grid sized for EXACT CU fills:
// gemm1 512 blocks (2 fills), gemm2 256 blocks (1 fill). XCD-bijective swizzle.

#define GLD(SRC, DST) __builtin_amdgcn_global_load_lds(GLOBAL_AS(SRC), LDS_AS(DST), 16, 0, 0)
#define WAITN(n) asm volatile("s_waitcnt vmcnt(" #n ")" ::: "memory")

// NBCH = B-tile 16B chunks = NFRAG*128. Extra B-load lanes: see STAGEW.
#define WAITSEL                                                                          \
  do {                                                                                   \
    if (NBCH >= 1024) { if (wex) WAITN(7); else WAITN(6); }                              \
    else              { if (wex) WAITN(6); else WAITN(5); }                              \
  } while (0)

#define STAGEW(KT, SB)                                                                   \
  do {                                                                                   \
    const u16* a_ = gA0 + (KT) * 64;                                                     \
    GLD(a_,            lA + (SB) * 16384 + t * 8);                                       \
    GLD(a_ + 64 * kk,  lA + (SB) * 16384 + (t + 512) * 8);                               \
    GLD(a_ + 128 * kk, lA + (SB) * 16384 + (t + 1024) * 8);                              \
    GLD(a_ + 192 * kk, lA + (SB) * 16384 + (t + 1536) * 8);                              \
    const u16* b_ = gB0 + (KT) * 64;                                                     \
    GLD(b_, lB + (SB) * TBSZ + t * 8);                                                   \
    if (NBCH >= 1024) {                                                                  \
      GLD(b_ + 64 * kk, lB + (SB) * TBSZ + (t + 512) * 8);                               \
      if (t < NBCH - 1024) GLD(b_ + 128 * kk, lB + (SB) * TBSZ + (t + 1024) * 8);        \
    } else {                                                                             \
      if (t < NBCH - 512) GLD(b_ + 64 * kk, lB + (SB) * TBSZ + (t + 512) * 8);           \
    }                                                                                    \
  } while (0)

#define ITERW(KT, CB, SB, DOSTAGE, FINAL)                                                \
  do {                                                                                   \
    if (FINAL) WAITN(0); else WAITSEL;                                                   \
    __builtin_amdgcn_s_barrier();                                                        \
    asm volatile("" ::: "memory");                                                       \
    if (DOSTAGE) STAGEW((KT) + 2, SB);                                                   \
    const u16* pa_ = lA + (CB) * 16384;                                                  \
    const u16* pb_ = lB + (CB) * TBSZ;                                                   \
    {                                                                                    \
      short8 a0 = *(const short8*)(pa_ + arow0 + cs0);                                   \
      short8 a1 = *(const short8*)(pa_ + arow1 + cs0);                                   \
      short8 bf[NFRAG];                                                                  \
      _Pragma("unroll")                                                                  \
      for (int ni = 0; ni < NFRAG; ++ni)                                                 \
        bf[ni] = *(const short8*)(pb_ + ni * 1024 + browb + cs0);                        \
      __builtin_amdgcn_s_setprio(1);                                                     \
      _Pragma("unroll")                                                                  \
      for (int ni = 0; ni < NFRAG; ++ni) {                                               \
        acc[0][ni] = __builtin_amdgcn_mfma_f32_16x16x32_bf16(a0, bf[ni], acc[0][ni], 0, 0, 0); \
        acc[1][ni] = __builtin_amdgcn_mfma_f32_16x16x32_bf16(a1, bf[ni], acc[1][ni], 0, 0, 0); \
      }                                                                                  \
      __builtin_amdgcn_s_setprio(0);                                                     \
    }                                                                                    \
    {                                                                                    \
      short8 a0 = *(const short8*)(pa_ + arow0 + cs1);                                   \
      short8 a1 = *(const short8*)(pa_ + arow1 + cs1);                                   \
      short8 bf[NFRAG];                                                                  \
      _Pragma("unroll")                                                                  \
      for (int ni = 0; ni < NFRAG; ++ni)                                                 \
        bf[ni] = *(const short8*)(pb_ + ni * 1024 + browb + cs1);                        \
      __builtin_amdgcn_s_setprio(1);                                                     \
      _Pragma("unroll")                                                                  \
      for (int ni = 0; ni < NFRAG; ++ni) {                                               \
        acc[0][ni] = __builtin_amdgcn_mfma_f32_16x16x32_bf16(a0, bf[ni], acc[0][ni], 0, 0, 0); \
        acc[1][ni] = __builtin_amdgcn_mfma_f32_16x16x32_bf16(a1, bf[ni], acc[1][ni], 0, 0, 0); \
      }                                                                                  \
      __builtin_amdgcn_s_setprio(0);                                                     \
    }                                                                                    \
  } while (0)

template <int EPI, int NFRAG>
__global__ __launch_bounds__(512, 2) void gemmW(
    const u16* __restrict__ A, const u16* __restrict__ Bt, void* __restrict__ Cout,
    const float* __restrict__ bias, int M, int N, int K, int NXP) {
  constexpr int NBCH = NFRAG * 128;   // B-tile 16B chunks (1152 / 768)
  constexpr int TBSZ = NFRAG * 1024;  // B-tile u16 size per buffer
  constexpr int EXW = (NBCH >= 1024 ? NBCH - 1024 : NBCH - 512) / 64;  // extra-load waves
  extern __shared__ u16 sm[];
  u16* lA = sm;                 // 3 bufs x 256x64 u16 = 96 KiB
  u16* lB = sm + 3 * 16384;     // 3 bufs x BNx64 u16
  const int t = threadIdx.x;
  const size_t kk = (size_t)K;
  const int nwg = gridDim.x;
  const int logical = (blockIdx.x & 7) * (nwg >> 3) + (blockIdx.x >> 3);
  const int m0 = (logical / NXP) * 256;
  const int n0 = (logical % NXP) * (NFRAG * 16);
  const int wv = t >> 6, l = t & 63;
  const int lr = l & 15, g = l >> 4;
  const bool wex = wv < EXW;

  // staging source (pre-swizzled): chunk c -> row c>>3, src chunk (c&7)^(row&7)
  const int ra = t >> 3;
  const int ca = (t & 7) ^ (ra & 7);
  const u16* gA0 = A + (size_t)(m0 + ra) * kk + ca * 8;
  const u16* gB0 = Bt + (size_t)(n0 + ra) * kk + ca * 8;

  // fragment ds_read offsets (u16): row r, k-chunk kc -> r*64 + (kc^(r&7))*8
  // all frag rows have row&7 == lr&7 (bases are multiples of 16)
  const int cs0 = ((g + 0) ^ (lr & 7)) * 8;
  const int cs1 = ((g + 4) ^ (lr & 7)) * 8;
  const int arow0 = (wv * 32 + lr) * 64, arow1 = (wv * 32 + 16 + lr) * 64;
  const int browb = lr * 64;

  f32x4 acc[2][NFRAG] = {};

  STAGEW(0, 0);
  STAGEW(1, 1);
  // K=768 -> 12 tiles. kt=0..9 stage kt+2; 10,11 drain.
  for (int j = 0; j < 3; ++j) {
    const int kt = j * 3;
    ITERW(kt + 0, 0, 2, 1, 0);
    ITERW(kt + 1, 1, 0, 1, 0);
    ITERW(kt + 2, 2, 1, 1, 0);
  }
  ITERW(9, 0, 2, 1, 0);
  ITERW(10, 1, 2, 0, 0);
  ITERW(11, 2, 2, 0, 1);

#pragma unroll
  for (int mi = 0; mi < 2; ++mi) {
    int row = m0 + wv * 32 + mi * 16 + g * 4;
#pragma unroll
    for (int ni = 0; ni < NFRAG; ++ni) {
      int col = n0 + ni * 16 + lr;
#pragma unroll
      for (int r = 0; r < 4; ++r) {
        float v = acc[mi][ni][r];
        if (EPI == 0) {
          ((u16*)Cout)[(size_t)(row + r) * N + col] = f2b(v);
        } else {
          ((float*)Cout)[(size_t)(row + r) * N + col] = v + bias[col];
        }
      }
    }
  }
}

// ---------------- local attention ----------------
// qkv: (B*N, 2304) bf16 rows: [q(768) | k(768) | v(768)], within each: h*64+d
#define NTILE 128
#define ROWS 140  // NTILE + 2*6
#define LPAD 66

__global__ __launch_bounds__(128) void attn_kernel(const u16* __restrict__ qkv,
                                                   u16* __restrict__ attn) {
  const int nt = blockIdx.x, h = blockIdx.y, b = blockIdx.z;
  const int n0 = nt * NTILE;
  const int t = threadIdx.x;
  __shared__ u16 kl[ROWS * LPAD];
  __shared__ u16 vl[ROWS * LPAD];

  for (int i = t; i < 2 * ROWS * 8; i += 128) {
    int mat = i >= ROWS * 8;
    int j = mat ? i - ROWS * 8 : i;
    int r = j >> 3, c = j & 7;
    int grow = n0 - 6 + r;
    grow = grow < 0 ? 0 : (grow > 4095 ? 4095 : grow);
    const uint4 u =
        *(const uint4*)(qkv + (size_t)(b * 4096 + grow) * 2304 + (mat ? 1536 : 768) + h * 64 + c * 8);
    u16* dst = (mat ? vl : kl) + r * LPAD + c * 8;
    ((u32*)dst)[0] = u.x;
    ((u32*)dst)[1] = u.y;
    ((u32*)dst)[2] = u.z;
    ((u32*)dst)[3] = u.w;
  }
  __syncthreads();

  const int wv = t >> 6, l = t & 63;
  const int n = n0 + wv * 64 + l;
  const int lrow = wv * 64 + l;

  float qf[64];
  const u16* qp = qkv + (size_t)(b * 4096 + n) * 2304 + h * 64;
#pragma unroll
  for (int c = 0; c < 8; ++c) {
    uint4 u = *(const uint4*)(qp + c * 8);
    qf[c * 8 + 0] = blo(u.x); qf[c * 8 + 1] = bhi(u.x);
    qf[c * 8 + 2] = blo(u.y); qf[c * 8 + 3] = bhi(u.y);
    qf[c * 8 + 4] = blo(u.z); qf[c * 8 + 5] = bhi(u.z);
    qf[c * 8 + 6] = blo(u.w); qf[c * 8 + 7] = bhi(u.w);
  }

  float s[13];
#pragma unroll
  for (int w = 0; w < 13; ++w) s[w] = 0.f;
#pragma unroll
  for (int d2 = 0; d2 < 32; ++d2) {
    float q0 = qf[2 * d2], q1 = qf[2 * d2 + 1];
#pragma unroll
    for (int w = 0; w < 13; ++w) {
      u32 u = *(const u32*)(kl + (lrow + w) * LPAD + 2 * d2);
      s[w] += q0 * blo(u) + q1 * bhi(u);
    }
  }

#pragma unroll
  for (int w = 0; w < 13; ++w) {
    int nn = n - 6 + w;
    s[w] = (nn >= 0 && nn < 4096) ? s[w] * 0.125f : -1e30f;
  }
  float m = s[0];
#pragma unroll
  for (int w = 1; w < 13; ++w) m = fmaxf(m, s[w]);
  float sum = 0.f;
#pragma unroll
  for (int w = 0; w < 13; ++w) {
    float p = __expf(s[w] - m);
    s[w] = p;
    sum += p;
  }
  float inv = 1.0f / sum;

  float o[64];
#pragma unroll
  for (int d = 0; d < 64; ++d) o[d] = 0.f;
#pragma unroll
  for (int w = 0; w < 13; ++w) {
    float pw = s[w] * inv;
#pragma unroll
    for (int d2 = 0; d2 < 32; ++d2) {
      u32 u = *(const u32*)(vl + (lrow + w) * LPAD + 2 * d2);
      o[2 * d2] += pw * blo(u);
      o[2 * d2 + 1] += pw * bhi(u);
    }
  }

  u16* op = attn + (size_t)(b * 4096 + n) * 768 + h * 64;
#pragma unroll
  for (int c = 0; c < 8; ++c) {
    uint4 u;
    u.x = (u32)f2b(o[c * 8 + 0]) | ((u32)f2b(o[c * 8 + 1]) << 16);
    u.y = (u32)f2b(o[c * 8 + 2]) | ((u32)f2b(o[c * 8 + 3]) << 16);
    u.z = (u32)f2b(o[c * 8 + 4]) | ((u32)f2b(o[c * 8 + 5]) << 16);
    u.w = (u32)f2b(o[c * 8 + 6]) | ((u32)f2b(o[c * 8 + 7]) << 16);
    ((uint4*)op)[c] = u;
  }
}

extern "C" void kernel_launch(void* const* d_in, const int* in_sizes, int n_in,
                              void* d_out, int out_size, void* d_ws, size_t ws_size,
                              hipStream_t stream) {
  const float* x = (const float*)d_in[0];
  const float* w_qkv = (const float*)d_in[1];
  const float* w_proj = (const float*)d_in[2];
  const float* b_proj = (const float*)d_in[3];
  float* out = (float*)d_out;

  char* p = (char*)d_ws;
  u16* xb = (u16*)p;     p += (size_t)8192 * 768 * 2;
  u16* wqT = (u16*)p;    p += (size_t)2304 * 768 * 2;
  u16* wpT = (u16*)p;    p += (size_t)768 * 768 * 2;
  u16* qkvb = (u16*)p;   p += (size_t)8192 * 2304 * 2;
  u16* attnb = (u16*)p;  p += (size_t)8192 * 768 * 2;

  // gemm1: BN=144 (NFRAG=9): LDS = 3*(32768 + 18432) = 150 KiB
  // gemm2: BN=96  (NFRAG=6): LDS = 3*(32768 + 12288) = 132 KiB
  const int lds1 = 3 * (32768 + 18432);
  const int lds2 = 3 * (32768 + 12288);
  hipFuncSetAttribute((const void*)gemmW<0, 9>, hipFuncAttributeMaxDynamicSharedMemorySize, lds1);
  hipFuncSetAttribute((const void*)gemmW<1, 6>, hipFuncAttributeMaxDynamicSharedMemorySize, lds2);

  conv_bf16<<<dim3(2048), dim3(256), 0, stream>>>(x, xb, 8192 * 768 / 4);
  transpose_conv2<<<dim3(72, 24, 2), dim3(32, 8), 0, stream>>>(w_qkv, wqT, w_proj, wpT);

  // gemm1: M=8192 (32 x 256), N=2304 (16 x 144) -> 512 blocks = 2 exact fills
  gemmW<0, 9><<<dim3(512), dim3(512), lds1, stream>>>(
      xb, wqT, (void*)qkvb, nullptr, 8192, 2304, 768, 16);

  attn_kernel<<<dim3(4096 / NTILE, 12, 2), dim3(128), 0, stream>>>(qkvb, attnb);

  // gemm2: M=8192 (32 x 256), N=768 (8 x 96) -> 256 blocks = 1 exact fill
  gemmW<1, 6><<<dim3(256), dim3(512), lds2, stream>>>(
      attnb, wpT, (void*)out, b_proj, 8192, 768, 768, 8);
}

// Round 10
// 151.231 us; speedup vs baseline: 1.3041x; 1.1239x over previous
//
#include <hip/hip_runtime.h>

typedef unsigned short u16;
typedef unsigned int u32;
typedef __attribute__((ext_vector_type(8))) short short8;
typedef __attribute__((ext_vector_type(4))) float f32x4;

#define GLOBAL_AS(p) (const __attribute__((address_space(1))) void*)(p)
#define LDS_AS(p) (__attribute__((address_space(3))) void*)(p)

__device__ __forceinline__ u16 f2b(float f) {
  u32 u = __float_as_uint(f);
  u32 r = (u + 0x7fffu + ((u >> 16) & 1u)) >> 16;
  return (u16)r;
}
__device__ __forceinline__ float blo(u32 u) { return __uint_as_float(u << 16); }
__device__ __forceinline__ float bhi(u32 u) { return __uint_as_float(u & 0xffff0000u); }

// ---------------- fp32 -> bf16 convert (x) ----------------
__global__ void conv_bf16(const float* __restrict__ in, u16* __restrict__ out, int n4) {
  int i = blockIdx.x * blockDim.x + threadIdx.x;
  int stride = gridDim.x * blockDim.x;
  for (; i < n4; i += stride) {
    float4 f = ((const float4*)in)[i];
    ushort4 u;
    u.x = f2b(f.x); u.y = f2b(f.y); u.z = f2b(f.z); u.w = f2b(f.w);
    ((ushort4*)out)[i] = u;
  }
}

// ---- fused weight transpose+convert: z=0 w_qkv(768x2304), z=1 w_proj(768x768) ----
__global__ void transpose_conv2(const float* __restrict__ w_qkv, u16* __restrict__ wqT,
                                const float* __restrict__ w_proj, u16* __restrict__ wpT) {
  __shared__ float tile[32][33];
  const int z = blockIdx.z;
  if (z && blockIdx.x >= 24) return;
  const float* in = z ? w_proj : w_qkv;
  u16* out = z ? wpT : wqT;
  const int Cc = z ? 768 : 2304;
  int c0 = blockIdx.x * 32, r0 = blockIdx.y * 32;
  int tx = threadIdx.x, ty = threadIdx.y;  // 32 x 8
#pragma unroll
  for (int i = 0; i < 32; i += 8)
    tile[ty + i][tx] = in[(size_t)(r0 + ty + i) * Cc + c0 + tx];
  __syncthreads();
#pragma unroll
  for (int i = 0; i < 32; i += 8)
    out[(size_t)(c0 + ty + i) * 768 + r0 + tx] = f2b(tile[tx][ty + i]);
}

// ---------------- GEMM: C = A(MxK) * Bt(NxK)^T, bf16 in, fp32 acc ----------------
// BM=256, BN=NFRAG*16 (144 or 96), BK=64, K=768 (12 tiles). 512 threads = 8
// waves, wave wv owns rows [wv*32, wv*32+32) x all BN cols. 3-buffer LDS ring,
// depth-2 prefetch, counted per-wave vmcnt, ONE barrier per K-iter, setprio.
// Swizzle chunk^=(row&7) on BOTH staging source and ds_read. Exact CU fills.

#define GLD(SRC, DST) __builtin_amdgcn_global_load_lds(GLOBAL_AS(SRC), LDS_AS(DST), 16, 0, 0)
#define WAITN(n) asm volatile("s_waitcnt vmcnt(" #n ")" ::: "memory")

#define WAITSEL                                                                          \
  do {                                                                                   \
    if (NBCH >= 1024) { if (wex) WAITN(7); else WAITN(6); }                              \
    else              { if (wex) WAITN(6); else WAITN(5); }                              \
  } while (0)

#define STAGEW(KT, SB)                                                                   \
  do {                                                                                   \
    const u16* a_ = gA0 + (KT) * 64;                                                     \
    GLD(a_,            lA + (SB) * 16384 + t * 8);                                       \
    GLD(a_ + 64 * kk,  lA + (SB) * 16384 + (t + 512) * 8);                               \
    GLD(a_ + 128 * kk, lA + (SB) * 16384 + (t + 1024) * 8);                              \
    GLD(a_ + 192 * kk, lA + (SB) * 16384 + (t + 1536) * 8);                              \
    const u16* b_ = gB0 + (KT) * 64;                                                     \
    GLD(b_, lB + (SB) * TBSZ + t * 8);                                                   \
    if (NBCH >= 1024) {                                                                  \
      GLD(b_ + 64 * kk, lB + (SB) * TBSZ + (t + 512) * 8);                               \
      if (t < NBCH - 1024) GLD(b_ + 128 * kk, lB + (SB) * TBSZ + (t + 1024) * 8);        \
    } else {                                                                             \
      if (t < NBCH - 512) GLD(b_ + 64 * kk, lB + (SB) * TBSZ + (t + 512) * 8);           \
    }                                                                                    \
  } while (0)

#define ITERW(KT, CB, SB, DOSTAGE, FINAL)                                                \
  do {                                                                                   \
    if (FINAL) WAITN(0); else WAITSEL;                                                   \
    __builtin_amdgcn_s_barrier();                                                        \
    asm volatile("" ::: "memory");                                                       \
    if (DOSTAGE) STAGEW((KT) + 2, SB);                                                   \
    const u16* pa_ = lA + (CB) * 16384;                                                  \
    const u16* pb_ = lB + (CB) * TBSZ;                                                   \
    {                                                                                    \
      short8 a0 = *(const short8*)(pa_ + arow0 + cs0);                                   \
      short8 a1 = *(const short8*)(pa_ + arow1 + cs0);                                   \
      short8 bf[NFRAG];                                                                  \
      _Pragma("unroll")                                                                  \
      for (int ni = 0; ni < NFRAG; ++ni)                                                 \
        bf[ni] = *(const short8*)(pb_ + ni * 1024 + browb + cs0);                        \
      __builtin_amdgcn_s_setprio(1);                                                     \
      _Pragma("unroll")                                                                  \
      for (int ni = 0; ni < NFRAG; ++ni) {                                               \
        acc[0][ni] = __builtin_amdgcn_mfma_f32_16x16x32_bf16(a0, bf[ni], acc[0][ni], 0, 0, 0); \
        acc[1][ni] = __builtin_amdgcn_mfma_f32_16x16x32_bf16(a1, bf[ni], acc[1][ni], 0, 0, 0); \
      }                                                                                  \
      __builtin_amdgcn_s_setprio(0);                                                     \
    }                                                                                    \
    {                                                                                    \
      short8 a0 = *(const short8*)(pa_ + arow0 + cs1);                                   \
      short8 a1 = *(const short8*)(pa_ + arow1 + cs1);                                   \
      short8 bf[NFRAG];                                                                  \
      _Pragma("unroll")                                                                  \
      for (int ni = 0; ni < NFRAG; ++ni)                                                 \
        bf[ni] = *(const short8*)(pb_ + ni * 1024 + browb + cs1);                        \
      __builtin_amdgcn_s_setprio(1);                                                     \
      _Pragma("unroll")                                                                  \
      for (int ni = 0; ni < NFRAG; ++ni) {                                               \
        acc[0][ni] = __builtin_amdgcn_mfma_f32_16x16x32_bf16(a0, bf[ni], acc[0][ni], 0, 0, 0); \
        acc[1][ni] = __builtin_amdgcn_mfma_f32_16x16x32_bf16(a1, bf[ni], acc[1][ni], 0, 0, 0); \
      }                                                                                  \
      __builtin_amdgcn_s_setprio(0);                                                     \
    }                                                                                    \
  } while (0)

template <int EPI, int NFRAG>
__global__ __launch_bounds__(512, 2) void gemmW(
    const u16* __restrict__ A, const u16* __restrict__ Bt, void* __restrict__ Cout,
    const float* __restrict__ bias, int M, int N, int K, int NXP) {
  constexpr int NBCH = NFRAG * 128;
  constexpr int TBSZ = NFRAG * 1024;
  constexpr int EXW = (NBCH >= 1024 ? NBCH - 1024 : NBCH - 512) / 64;
  extern __shared__ u16 sm[];
  u16* lA = sm;
  u16* lB = sm + 3 * 16384;
  const int t = threadIdx.x;
  const size_t kk = (size_t)K;
  const int nwg = gridDim.x;
  const int logical = (blockIdx.x & 7) * (nwg >> 3) + (blockIdx.x >> 3);
  const int m0 = (logical / NXP) * 256;
  const int n0 = (logical % NXP) * (NFRAG * 16);
  const int wv = t >> 6, l = t & 63;
  const int lr = l & 15, g = l >> 4;
  const bool wex = wv < EXW;

  const int ra = t >> 3;
  const int ca = (t & 7) ^ (ra & 7);
  const u16* gA0 = A + (size_t)(m0 + ra) * kk + ca * 8;
  const u16* gB0 = Bt + (size_t)(n0 + ra) * kk + ca * 8;

  const int cs0 = ((g + 0) ^ (lr & 7)) * 8;
  const int cs1 = ((g + 4) ^ (lr & 7)) * 8;
  const int arow0 = (wv * 32 + lr) * 64, arow1 = (wv * 32 + 16 + lr) * 64;
  const int browb = lr * 64;

  f32x4 acc[2][NFRAG] = {};

  STAGEW(0, 0);
  STAGEW(1, 1);
  for (int j = 0; j < 3; ++j) {
    const int kt = j * 3;
    ITERW(kt + 0, 0, 2, 1, 0);
    ITERW(kt + 1, 1, 0, 1, 0);
    ITERW(kt + 2, 2, 1, 1, 0);
  }
  ITERW(9, 0, 2, 1, 0);
  ITERW(10, 1, 2, 0, 0);
  ITERW(11, 2, 2, 0, 1);

#pragma unroll
  for (int mi = 0; mi < 2; ++mi) {
    int row = m0 + wv * 32 + mi * 16 + g * 4;
#pragma unroll
    for (int ni = 0; ni < NFRAG; ++ni) {
      int col = n0 + ni * 16 + lr;
#pragma unroll
      for (int r = 0; r < 4; ++r) {
        float v = acc[mi][ni][r];
        if (EPI == 0) {
          ((u16*)Cout)[(size_t)(row + r) * N + col] = f2b(v);
        } else {
          ((float*)Cout)[(size_t)(row + r) * N + col] = v + bias[col];
        }
      }
    }
  }
}

// ---------------- local attention (4 threads per row) ----------------
// qkv: (B*N, 2304) bf16 rows: [q | k | v], within each: h*64+d.
// Block: 512 threads = (row r = t>>2, quarter p = t&3), NTILE=128 rows, 1 head.
// Each thread: QK over its 16 d's -> quad shfl_xor reduce -> softmax (replicated)
// -> PV over its 16 d's. 24 waves/CU (3 blocks x 8 waves).
#define NTILE 128
#define ROWS 140  // NTILE + 2*6
#define LPAD 66

__global__ __launch_bounds__(512, 6) void attn_kernel(const u16* __restrict__ qkv,
                                                      u16* __restrict__ attn) {
  const int nt = blockIdx.x, h = blockIdx.y, b = blockIdx.z;
  const int n0 = nt * NTILE;
  const int t = threadIdx.x;
  __shared__ u16 kl[ROWS * LPAD];
  __shared__ u16 vl[ROWS * LPAD];

  // stage K and V window rows [n0-6, n0+133] (clamped) into LDS
  for (int i = t; i < 2 * ROWS * 8; i += 512) {
    int mat = i >= ROWS * 8;
    int j = mat ? i - ROWS * 8 : i;
    int r = j >> 3, c = j & 7;
    int grow = n0 - 6 + r;
    grow = grow < 0 ? 0 : (grow > 4095 ? 4095 : grow);
    const uint4 u =
        *(const uint4*)(qkv + (size_t)(b * 4096 + grow) * 2304 + (mat ? 1536 : 768) + h * 64 + c * 8);
    u16* dst = (mat ? vl : kl) + r * LPAD + c * 8;
    ((u32*)dst)[0] = u.x;
    ((u32*)dst)[1] = u.y;
    ((u32*)dst)[2] = u.z;
    ((u32*)dst)[3] = u.w;
  }
  __syncthreads();

  const int r = t >> 2;      // row in tile, 0..127
  const int p = t & 3;       // d-quarter, 0..3
  const int n = n0 + r;
  const int dbase = p * 16;  // u16 offset of this quarter within the head slice

  // q quarter into registers (fp32): d = p*16 .. p*16+15
  float qf[16];
  const u16* qp = qkv + (size_t)(b * 4096 + n) * 2304 + h * 64 + dbase;
#pragma unroll
  for (int c = 0; c < 2; ++c) {
    uint4 u = *(const uint4*)(qp + c * 8);
    qf[c * 8 + 0] = blo(u.x); qf[c * 8 + 1] = bhi(u.x);
    qf[c * 8 + 2] = blo(u.y); qf[c * 8 + 3] = bhi(u.y);
    qf[c * 8 + 4] = blo(u.z); qf[c * 8 + 5] = bhi(u.z);
    qf[c * 8 + 6] = blo(u.w); qf[c * 8 + 7] = bhi(u.w);
  }

  // partial scores over this quarter's 16 d's
  float s[13];
#pragma unroll
  for (int w = 0; w < 13; ++w) s[w] = 0.f;
#pragma unroll
  for (int d2 = 0; d2 < 8; ++d2) {
    float q0 = qf[2 * d2], q1 = qf[2 * d2 + 1];
#pragma unroll
    for (int w = 0; w < 13; ++w) {
      u32 u = *(const u32*)(kl + (r + w) * LPAD + dbase + 2 * d2);
      s[w] += q0 * blo(u) + q1 * bhi(u);
    }
  }
  // quad reduce: lanes 4r..4r+3 hold partials of the same row
#pragma unroll
  for (int w = 0; w < 13; ++w) {
    s[w] += __shfl_xor(s[w], 1);
    s[w] += __shfl_xor(s[w], 2);
  }

  // mask + softmax (fp32, replicated across the quad)
#pragma unroll
  for (int w = 0; w < 13; ++w) {
    int nn = n - 6 + w;
    s[w] = (nn >= 0 && nn < 4096) ? s[w] * 0.125f : -1e30f;
  }
  float m = s[0];
#pragma unroll
  for (int w = 1; w < 13; ++w) m = fmaxf(m, s[w]);
  float sum = 0.f;
#pragma unroll
  for (int w = 0; w < 13; ++w) {
    float pr = __expf(s[w] - m);
    s[w] = pr;
    sum += pr;
  }
  float inv = 1.0f / sum;

  // PV over this quarter's 16 d's
  float o[16];
#pragma unroll
  for (int d = 0; d < 16; ++d) o[d] = 0.f;
#pragma unroll
  for (int w = 0; w < 13; ++w) {
    float pw = s[w] * inv;
#pragma unroll
    for (int d2 = 0; d2 < 8; ++d2) {
      u32 u = *(const u32*)(vl + (r + w) * LPAD + dbase + 2 * d2);
      o[2 * d2] += pw * blo(u);
      o[2 * d2 + 1] += pw * bhi(u);
    }
  }

  u16* op = attn + (size_t)(b * 4096 + n) * 768 + h * 64 + dbase;
#pragma unroll
  for (int c = 0; c < 2; ++c) {
    uint4 u;
    u.x = (u32)f2b(o[c * 8 + 0]) | ((u32)f2b(o[c * 8 + 1]) << 16);
    u.y = (u32)f2b(o[c * 8 + 2]) | ((u32)f2b(o[c * 8 + 3]) << 16);
    u.z = (u32)f2b(o[c * 8 + 4]) | ((u32)f2b(o[c * 8 + 5]) << 16);
    u.w = (u32)f2b(o[c * 8 + 6]) | ((u32)f2b(o[c * 8 + 7]) << 16);
    ((uint4*)op)[c] = u;
  }
}

extern "C" void kernel_launch(void* const* d_in, const int* in_sizes, int n_in,
                              void* d_out, int out_size, void* d_ws, size_t ws_size,
                              hipStream_t stream) {
  const float* x = (const float*)d_in[0];
  const float* w_qkv = (const float*)d_in[1];
  const float* w_proj = (const float*)d_in[2];
  const float* b_proj = (const float*)d_in[3];
  float* out = (float*)d_out;

  char* p = (char*)d_ws;
  u16* xb = (u16*)p;     p += (size_t)8192 * 768 * 2;
  u16* wqT = (u16*)p;    p += (size_t)2304 * 768 * 2;
  u16* wpT = (u16*)p;    p += (size_t)768 * 768 * 2;
  u16* qkvb = (u16*)p;   p += (size_t)8192 * 2304 * 2;
  u16* attnb = (u16*)p;  p += (size_t)8192 * 768 * 2;

  const int lds1 = 3 * (32768 + 18432);
  const int lds2 = 3 * (32768 + 12288);
  hipFuncSetAttribute((const void*)gemmW<0, 9>, hipFuncAttributeMaxDynamicSharedMemorySize, lds1);
  hipFuncSetAttribute((const void*)gemmW<1, 6>, hipFuncAttributeMaxDynamicSharedMemorySize, lds2);

  conv_bf16<<<dim3(2048), dim3(256), 0, stream>>>(x, xb, 8192 * 768 / 4);
  transpose_conv2<<<dim3(72, 24, 2), dim3(32, 8), 0, stream>>>(w_qkv, wqT, w_proj, wpT);

  // gemm1: M=8192 (32 x 256), N=2304 (16 x 144) -> 512 blocks = 2 exact fills
  gemmW<0, 9><<<dim3(512), dim3(512), lds1, stream>>>(
      xb, wqT, (void*)qkvb, nullptr, 8192, 2304, 768, 16);

  attn_kernel<<<dim3(4096 / NTILE, 12, 2), dim3(512), 0, stream>>>(qkvb, attnb);

  // gemm2: M=8192 (32 x 256), N=768 (8 x 96) -> 256 blocks = 1 exact fill
  gemmW<1, 6><<<dim3(256), dim3(512), lds2, stream>>>(
      attnb, wpT, (void*)out, b_proj, 8192, 768, 768, 8);
}